// Round 4
// baseline (883.323 us; speedup 1.0000x reference)
//
#include <hip/hip_runtime.h>
#include <math.h>

#define NN 30000
#define EE 480000
#define FD 256
#define CH 128
#define NCLS 16
#define GH 64
#define MH 128
#define BT 4096
#define EPSc 1e-8f
#define GBc ((NN + 127) / 128)
#define SPB8 ((NN + 7) / 8)
#define SPB16 ((NN + 15) / 16)
#define RBc ((BT + 15) / 16)
#define NOX (SPB16 + 3 * RBc)   // 1875 + 768 = 2643 "other" blocks in mega23

typedef __attribute__((ext_vector_type(8))) short short8;
typedef __attribute__((ext_vector_type(4))) float f32x4;

// ---------- helpers ----------
__device__ __forceinline__ unsigned short f2bf(float x) {
    unsigned b = __float_as_uint(x);
    unsigned r = b + 0x7FFFu + ((b >> 16) & 1u);
    return (unsigned short)(r >> 16);
}
__device__ __forceinline__ float bf2f(unsigned short h) {
    return __uint_as_float(((unsigned)h) << 16);
}
__device__ __forceinline__ float4 fma4(float s, float4 x, float4 a) {
    a.x = fmaf(s, x.x, a.x); a.y = fmaf(s, x.y, a.y);
    a.z = fmaf(s, x.z, a.z); a.w = fmaf(s, x.w, a.w);
    return a;
}

// ---------- splits ----------
__global__ void split_bf16(const float* __restrict__ x, unsigned short* __restrict__ hi,
                           unsigned short* __restrict__ lo, long n) {
    long i = (long)blockIdx.x * 256 + threadIdx.x;
    if (i >= n) return;
    float v = x[i];
    unsigned short h = f2bf(v);
    hi[i] = h;
    lo[i] = f2bf(v - bf2f(h));
}

struct WSArgs {
    const float* s[8];
    unsigned short* h[8];
    unsigned short* l[8];
};
__global__ void wsplit_all(WSArgs a) {
    constexpr int NNp[8] = {64, 64, 128, 128, 128, 128, 128, 128};
    constexpr int OFF[9] = {0, 16384, 32768, 65536, 98304, 131072, 163840, 196608, 229376};
    int i = blockIdx.x * 256 + threadIdx.x;
    if (i >= 229376) return;
    int w = 0;
#pragma unroll
    for (int t = 1; t < 8; t++) if (i >= OFF[t]) w = t;
    int j = i - OFF[w];
    int N = NNp[w];
    int k = j / N, n = j % N;
    float v = a.s[w][j];
    unsigned short hh = f2bf(v);
    a.h[w][(size_t)n * 256 + k] = hh;
    a.l[w][(size_t)n * 256 + k] = f2bf(v - bf2f(hh));
}

// ---------- GEMM bodies ----------
template <int NT, bool OUT16>
__device__ __forceinline__ void gemm3_body(
    unsigned short* sm, int bx,
    const unsigned short* __restrict__ Ahi, const unsigned short* __restrict__ Alo,
    const unsigned short* __restrict__ BThi, const unsigned short* __restrict__ BTlo,
    int K, void* __restrict__ Cv, int Cstride, int M)
{
    unsigned short* Ah = sm;
    unsigned short* Al = Ah + 128 * 40;
    unsigned short* Bh = Al + 128 * 40;
    unsigned short* Bl = Bh + NT * 16 * 40;
    int t = threadIdx.x;
    int w = t >> 6, l = t & 63;
    int lane = l & 15, quad = l >> 4;
    int row0 = bx * 128;
    f32x4 acc[2][NT];
#pragma unroll
    for (int s = 0; s < 2; s++)
#pragma unroll
        for (int n = 0; n < NT; n++) acc[s][n] = (f32x4)(0.f);

    int ar = t >> 1, ako = (t & 1) << 4;
    int nkc = K >> 5;
    for (int kc = 0; kc < nkc; kc++) {
        int kb = kc << 5;
        {
            int gr = row0 + ar;
            float4 h0, h1, l0, l1;
            if (gr < M) {
                const float4* pH = (const float4*)&Ahi[(size_t)gr * K + kb + ako];
                const float4* pL = (const float4*)&Alo[(size_t)gr * K + kb + ako];
                h0 = pH[0]; h1 = pH[1]; l0 = pL[0]; l1 = pL[1];
            } else {
                h0 = h1 = l0 = l1 = make_float4(0.f, 0.f, 0.f, 0.f);
            }
            float4* dH = (float4*)&Ah[ar * 40 + ako];
            dH[0] = h0; dH[1] = h1;
            float4* dL = (float4*)&Al[ar * 40 + ako];
            dL[0] = l0; dL[1] = l1;
        }
        if (ar < NT * 16) {
            const float4* pH = (const float4*)&BThi[(size_t)ar * K + kb + ako];
            const float4* pL = (const float4*)&BTlo[(size_t)ar * K + kb + ako];
            float4 h0 = pH[0], h1 = pH[1], l0 = pL[0], l1 = pL[1];
            float4* dH = (float4*)&Bh[ar * 40 + ako];
            dH[0] = h0; dH[1] = h1;
            float4* dL = (float4*)&Bl[ar * 40 + ako];
            dL[0] = l0; dL[1] = l1;
        }
        __syncthreads();
        short8 aH[2], aL[2];
#pragma unroll
        for (int s = 0; s < 2; s++) {
            int r = w * 32 + s * 16 + lane;
            aH[s] = *(const short8*)&Ah[r * 40 + quad * 8];
            aL[s] = *(const short8*)&Al[r * 40 + quad * 8];
        }
#pragma unroll
        for (int n = 0; n < NT; n++) {
            int r = n * 16 + lane;
            short8 bH = *(const short8*)&Bh[r * 40 + quad * 8];
            short8 bL = *(const short8*)&Bl[r * 40 + quad * 8];
#pragma unroll
            for (int s = 0; s < 2; s++) {
                acc[s][n] = __builtin_amdgcn_mfma_f32_16x16x32_bf16(aH[s], bH, acc[s][n], 0, 0, 0);
                acc[s][n] = __builtin_amdgcn_mfma_f32_16x16x32_bf16(aH[s], bL, acc[s][n], 0, 0, 0);
                acc[s][n] = __builtin_amdgcn_mfma_f32_16x16x32_bf16(aL[s], bH, acc[s][n], 0, 0, 0);
            }
        }
        __syncthreads();
    }
#pragma unroll
    for (int s = 0; s < 2; s++) {
        int rb = row0 + w * 32 + s * 16 + quad * 4;
#pragma unroll
        for (int reg = 0; reg < 4; reg++) {
            int gr = rb + reg;
            if (gr >= M) continue;
#pragma unroll
            for (int n = 0; n < NT; n++) {
                if (OUT16)
                    ((unsigned short*)Cv)[(size_t)gr * Cstride + n * 16 + lane] = f2bf(acc[s][n][reg]);
                else
                    ((float*)Cv)[(size_t)gr * Cstride + n * 16 + lane] = acc[s][n][reg];
            }
        }
    }
}

template <int NT, bool OUT16>
__device__ __forceinline__ void gemm1_body(
    unsigned short* sm, int bx,
    const unsigned short* __restrict__ Ahi,
    const unsigned short* __restrict__ BThi,
    int K, void* __restrict__ Cv, int Cstride, int M)
{
    unsigned short* Ah = sm;
    unsigned short* Bh = Ah + 128 * 40;
    int t = threadIdx.x;
    int w = t >> 6, l = t & 63;
    int lane = l & 15, quad = l >> 4;
    int row0 = bx * 128;
    f32x4 acc[2][NT];
#pragma unroll
    for (int s = 0; s < 2; s++)
#pragma unroll
        for (int n = 0; n < NT; n++) acc[s][n] = (f32x4)(0.f);

    int ar = t >> 1, ako = (t & 1) << 4;
    int nkc = K >> 5;
    for (int kc = 0; kc < nkc; kc++) {
        int kb = kc << 5;
        {
            int gr = row0 + ar;
            float4 h0, h1;
            if (gr < M) {
                const float4* pH = (const float4*)&Ahi[(size_t)gr * K + kb + ako];
                h0 = pH[0]; h1 = pH[1];
            } else {
                h0 = h1 = make_float4(0.f, 0.f, 0.f, 0.f);
            }
            float4* dH = (float4*)&Ah[ar * 40 + ako];
            dH[0] = h0; dH[1] = h1;
        }
        if (ar < NT * 16) {
            const float4* pH = (const float4*)&BThi[(size_t)ar * K + kb + ako];
            float4 h0 = pH[0], h1 = pH[1];
            float4* dH = (float4*)&Bh[ar * 40 + ako];
            dH[0] = h0; dH[1] = h1;
        }
        __syncthreads();
        short8 aH[2];
#pragma unroll
        for (int s = 0; s < 2; s++)
            aH[s] = *(const short8*)&Ah[(w * 32 + s * 16 + lane) * 40 + quad * 8];
#pragma unroll
        for (int n = 0; n < NT; n++) {
            short8 bH = *(const short8*)&Bh[(n * 16 + lane) * 40 + quad * 8];
#pragma unroll
            for (int s = 0; s < 2; s++)
                acc[s][n] = __builtin_amdgcn_mfma_f32_16x16x32_bf16(aH[s], bH, acc[s][n], 0, 0, 0);
        }
        __syncthreads();
    }
#pragma unroll
    for (int s = 0; s < 2; s++) {
        int rb = row0 + w * 32 + s * 16 + quad * 4;
#pragma unroll
        for (int reg = 0; reg < 4; reg++) {
            int gr = rb + reg;
            if (gr >= M) continue;
#pragma unroll
            for (int n = 0; n < NT; n++) {
                if (OUT16)
                    ((unsigned short*)Cv)[(size_t)gr * Cstride + n * 16 + lane] = f2bf(acc[s][n][reg]);
                else
                    ((float*)Cv)[(size_t)gr * Cstride + n * 16 + lane] = acc[s][n][reg];
            }
        }
    }
}

// ---------- mega0: count(+seq) || gemm1 Ph2 || gemm1 Pmi×3 ----------
__global__ __launch_bounds__(256) void mega0(
    const int* __restrict__ i1, const int* __restrict__ i2, int* __restrict__ cnt,
    int* __restrict__ sd1, int* __restrict__ sd2,
    int* __restrict__ sc1, int* __restrict__ sc2,
    const unsigned short* __restrict__ feat_hi,
    const unsigned short* __restrict__ w1vh, unsigned short* __restrict__ Ph2,
    const unsigned short* __restrict__ wgallh, unsigned short* __restrict__ Pmi16)
{
    __shared__ unsigned short sm[128 * 40 + 8 * 16 * 40];
    int b = blockIdx.x;
    if (b < GBc) {
        gemm1_body<8, true>(sm, b, feat_hi, w1vh, FD, Ph2, 128, NN);
        return;
    }
    b -= GBc;
    if (b < 3 * GBc) {
        int y = b / GBc, bx = b % GBc;
        gemm1_body<8, true>(sm, bx, feat_hi, wgallh + (size_t)y * 32768,
                            FD, Pmi16 + (size_t)y * 128, 384, NN);
        return;
    }
    b -= 3 * GBc;
    int e = b * 256 + threadIdx.x;
    if (e >= EE) return;
    int r1 = i1[e], c1 = i1[EE + e];
    int r2 = i2[e], c2 = i2[EE + e];
    sd1[e] = atomicAdd(&cnt[r1], 1);
    sd2[e] = atomicAdd(&cnt[NN + r2], 1);
    sc1[e] = atomicAdd(&cnt[2 * NN + c1], 1);
    sc2[e] = atomicAdd(&cnt[3 * NN + c2], 1);
}

// ---------- mega1: atomic-free place || gemm3 Pg || gemm3 P01 ×2 ----------
__global__ __launch_bounds__(256) void mega1(
    const int* __restrict__ i1, const float* __restrict__ v1,
    const int* __restrict__ i2, const float* __restrict__ v2,
    const int* __restrict__ sd1, const int* __restrict__ sd2,
    const int* __restrict__ sc1, const int* __restrict__ sc2,
    const int* __restrict__ rp4,
    int2* __restrict__ ed1, int2* __restrict__ ec1,
    int2* __restrict__ ed2, int2* __restrict__ ec2,
    const unsigned short* __restrict__ feat_hi, const unsigned short* __restrict__ feat_lo,
    const unsigned short* __restrict__ wgen12h, const unsigned short* __restrict__ wgen12l,
    float* __restrict__ Pg,
    const unsigned short* __restrict__ w1pairh, const unsigned short* __restrict__ w1pairl,
    float* __restrict__ P01)
{
    __shared__ unsigned short sm[128 * 40 * 2 + 8 * 16 * 40 * 2];
    int b = blockIdx.x;
    if (b < GBc) {
        gemm3_body<8, false>(sm, b, feat_hi, feat_lo, wgen12h, wgen12l, FD, Pg, 128, NN);
        return;
    }
    b -= GBc;
    if (b < 2 * GBc) {
        int y = b / GBc, bx = b % GBc;
        gemm3_body<8, false>(sm, bx, feat_hi, feat_lo,
                             w1pairh + (size_t)y * 32768, w1pairl + (size_t)y * 32768,
                             FD, P01 + (size_t)y * 128, 256, NN);
        return;
    }
    b -= 2 * GBc;
    int e = b * 256 + threadIdx.x;
    if (e >= EE) return;
    const int* rp_d1 = rp4;
    const int* rp_d2 = rp4 + (NN + 1);
    const int* rp_c1 = rp4 + 2 * (NN + 1);
    const int* rp_c2 = rp4 + 3 * (NN + 1);
    int r = i1[e], c = i1[EE + e];
    int p = rp_d1[r] + sd1[e];
    ed1[p] = make_int2(c, __float_as_int(v1[e]));
    ec1[rp_c1[c] + sc1[e]] = make_int2(r, p);
    r = i2[e]; c = i2[EE + e];
    p = rp_d2[r] + sd2[e];
    ed2[p] = make_int2(c, __float_as_int(v2[e]));
    ec2[rp_c2[c] + sc2[e]] = make_int2(r, p);
}

// ---------- contrast ----------
__global__ __launch_bounds__(256) void contrast_direct(
    const unsigned short* __restrict__ z16, float* __restrict__ stats)
{
    int p = blockIdx.z;
    int pa = (p == 2) ? 1 : 0;
    int pb = (p == 0) ? 1 : 2;
    const unsigned short* A = z16 + (size_t)pa * BT * MH;
    const unsigned short* B = z16 + (size_t)pb * BT * MH;
    float* diag = stats + (size_t)p * 3 * BT;
    float* rs = diag + BT;
    float* cs = rs + BT;
    int t = threadIdx.x;
    int w = t >> 6, l = t & 63, m = l & 15, quad = l >> 4;
    int i0 = blockIdx.y * 128, j0 = blockIdx.x * 128;

    short8 afr[2][4];
#pragma unroll
    for (int s = 0; s < 2; s++) {
        const unsigned short* arow = &A[(size_t)(i0 + w * 32 + s * 16 + m) * MH + quad * 8];
#pragma unroll
        for (int kc = 0; kc < 4; kc++)
            afr[s][kc] = *(const short8*)(arow + kc * 32);
    }
    f32x4 acc[2][8];
#pragma unroll
    for (int s = 0; s < 2; s++)
#pragma unroll
        for (int n = 0; n < 8; n++) acc[s][n] = (f32x4)(0.f);

#pragma unroll
    for (int kc = 0; kc < 4; kc++) {
#pragma unroll
        for (int n = 0; n < 8; n++) {
            short8 bf = *(const short8*)&B[(size_t)(j0 + n * 16 + m) * MH + kc * 32 + quad * 8];
            acc[0][n] = __builtin_amdgcn_mfma_f32_16x16x32_bf16(afr[0][kc], bf, acc[0][n], 0, 0, 0);
            acc[1][n] = __builtin_amdgcn_mfma_f32_16x16x32_bf16(afr[1][kc], bf, acc[1][n], 0, 0, 0);
        }
    }
    float colp[8];
#pragma unroll
    for (int n = 0; n < 8; n++) colp[n] = 0.f;
#pragma unroll
    for (int s = 0; s < 2; s++) {
        int rbase = i0 + w * 32 + s * 16 + quad * 4;
#pragma unroll
        for (int reg = 0; reg < 4; reg++) {
            float rsum = 0.f;
            int gi = rbase + reg;
#pragma unroll
            for (int n = 0; n < 8; n++) {
                float mv = expf(acc[s][n][reg] * 2.0f);
                rsum += mv;
                colp[n] += mv;
                int gj = j0 + n * 16 + m;
                if (gi == gj) diag[gi] = mv;
            }
            rsum += __shfl_xor(rsum, 1); rsum += __shfl_xor(rsum, 2);
            rsum += __shfl_xor(rsum, 4); rsum += __shfl_xor(rsum, 8);
            if (m == 0) atomicAdd(&rs[gi], rsum);
        }
    }
    __shared__ float scol[128];
    if (t < 128) scol[t] = 0.f;
    __syncthreads();
#pragma unroll
    for (int n = 0; n < 8; n++) {
        float v = colp[n];
        v += __shfl_xor(v, 16); v += __shfl_xor(v, 32);
        if (quad == (n & 3)) atomicAdd(&scol[n * 16 + m], v);
    }
    __syncthreads();
    if (t < 128) atomicAdd(&cs[j0 + t], scol[t]);
}

// ---------- scans ----------
__global__ __launch_bounds__(1024) void scan_block4(const int* __restrict__ cnt,
                                                    int* __restrict__ rowptr,
                                                    int* __restrict__ bsum) {
    int y = blockIdx.y;
    int* rp = rowptr + y * (NN + 1);
    int* bs = bsum + y * 32;
    __shared__ int tmp[1024];
    int t = threadIdx.x;
    int i = blockIdx.x * 1024 + t;
    int v = (i < NN) ? cnt[y * NN + i] : 0;
    tmp[t] = v;
    __syncthreads();
    for (int off = 1; off < 1024; off <<= 1) {
        int add = (t >= off) ? tmp[t - off] : 0;
        __syncthreads();
        tmp[t] += add;
        __syncthreads();
    }
    if (i <= NN) rp[i] = tmp[t] - v;
    if (t == 1023) bs[blockIdx.x] = tmp[1023];
}
__global__ void scan_bsum4(int* __restrict__ bsum, int nb) {
    bsum += blockIdx.x * 32;
    int t = threadIdx.x;
    int orig = (t < nb) ? bsum[t] : 0;
    int v = orig;
    for (int off = 1; off < 64; off <<= 1) {
        int u = __shfl_up(v, off);
        if (t >= off) v += u;
    }
    if (t < nb) bsum[t] = v - orig;
}
__global__ void scan_add4(const int* __restrict__ bsum, int* __restrict__ rowptr) {
    int y = blockIdx.y;
    const int* bs = bsum + y * 32;
    int* rp = rowptr + y * (NN + 1);
    int i = blockIdx.x * 1024 + threadIdx.x;
    if (i <= NN) rp[i] += bs[blockIdx.x];
}

// ---------- row-parallel nv ----------
__global__ __launch_bounds__(256) void gen_nv(
    const int* __restrict__ rp_d, int2* __restrict__ ed1, int2* __restrict__ ed2,
    const float* __restrict__ sb, float* __restrict__ nvd1, float* __restrict__ nvd2)
{
    int y = blockIdx.y;
    int row = blockIdx.x * 256 + threadIdx.x;
    if (row >= NN) return;
    const int* rp = rp_d + y * (NN + 1);
    int2* ed = y ? ed2 : ed1;
    float* nvd = y ? nvd2 : nvd1;
    const float* sbv = sb + (size_t)y * NN;
    int p0 = rp[row], p1 = rp[row + 1];
    float m = -3.4e38f, sum = 0.f;
    for (int j = p0; j < p1; j++) {
        float x = sbv[ed[j].x];
        if (x > m) { sum = sum * expf(m - x) + 1.f; m = x; }
        else sum += expf(x - m);
    }
    float inv = 1.f / sum;
    for (int j = p0; j < p1; j++) {
        int2 q = ed[j];
        float nv = __int_as_float(q.y) + 0.5f * expf(sbv[q.x] - m) * inv;
        nvd[j] = nv;
        ed[j].y = __float_as_int(nv);
    }
}

// ---------- fp32 gather helpers (8-deep MLP) ----------
template <int STR4>
__device__ __forceinline__ void gath_dir_f32(
    const int* __restrict__ rp, const int2* __restrict__ ed, int row,
    const float4* __restrict__ x4, int xo, float4* a)
{
    int p0 = rp[row], p1 = rp[row + 1];
    int j = p0;
    for (; j + 8 <= p1; j += 8) {
        int2 q0 = ed[j], q1 = ed[j+1], q2 = ed[j+2], q3 = ed[j+3];
        int2 q4 = ed[j+4], q5 = ed[j+5], q6 = ed[j+6], q7 = ed[j+7];
        float4 x0 = x4[(size_t)q0.x * STR4 + xo];
        float4 x1 = x4[(size_t)q1.x * STR4 + xo];
        float4 x2 = x4[(size_t)q2.x * STR4 + xo];
        float4 x3 = x4[(size_t)q3.x * STR4 + xo];
        float4 x5 = x4[(size_t)q4.x * STR4 + xo];
        float4 x6 = x4[(size_t)q5.x * STR4 + xo];
        float4 x7 = x4[(size_t)q6.x * STR4 + xo];
        float4 x8 = x4[(size_t)q7.x * STR4 + xo];
        a[0] = fma4(__int_as_float(q0.y), x0, a[0]);
        a[1] = fma4(__int_as_float(q1.y), x1, a[1]);
        a[2] = fma4(__int_as_float(q2.y), x2, a[2]);
        a[3] = fma4(__int_as_float(q3.y), x3, a[3]);
        a[0] = fma4(__int_as_float(q4.y), x5, a[0]);
        a[1] = fma4(__int_as_float(q5.y), x6, a[1]);
        a[2] = fma4(__int_as_float(q6.y), x7, a[2]);
        a[3] = fma4(__int_as_float(q7.y), x8, a[3]);
    }
    for (; j + 4 <= p1; j += 4) {
        int2 q0 = ed[j], q1 = ed[j+1], q2 = ed[j+2], q3 = ed[j+3];
        a[0] = fma4(__int_as_float(q0.y), x4[(size_t)q0.x * STR4 + xo], a[0]);
        a[1] = fma4(__int_as_float(q1.y), x4[(size_t)q1.x * STR4 + xo], a[1]);
        a[2] = fma4(__int_as_float(q2.y), x4[(size_t)q2.x * STR4 + xo], a[2]);
        a[3] = fma4(__int_as_float(q3.y), x4[(size_t)q3.x * STR4 + xo], a[3]);
    }
    for (; j < p1; j++) {
        int2 q = ed[j];
        a[0] = fma4(__int_as_float(q.y), x4[(size_t)q.x * STR4 + xo], a[0]);
    }
}
template <int STR4>
__device__ __forceinline__ void gath_csc_f32(
    const int* __restrict__ rp, const int2* __restrict__ ec, const float* __restrict__ nvd,
    int row, const float4* __restrict__ x4, int xo, float4* a)
{
    int p0 = rp[row], p1 = rp[row + 1];
    int j = p0;
    for (; j + 8 <= p1; j += 8) {
        int2 q0 = ec[j], q1 = ec[j+1], q2 = ec[j+2], q3 = ec[j+3];
        int2 q4 = ec[j+4], q5 = ec[j+5], q6 = ec[j+6], q7 = ec[j+7];
        float4 x0 = x4[(size_t)q0.x * STR4 + xo];
        float4 x1 = x4[(size_t)q1.x * STR4 + xo];
        float4 x2 = x4[(size_t)q2.x * STR4 + xo];
        float4 x3 = x4[(size_t)q3.x * STR4 + xo];
        float4 x5 = x4[(size_t)q4.x * STR4 + xo];
        float4 x6 = x4[(size_t)q5.x * STR4 + xo];
        float4 x7 = x4[(size_t)q6.x * STR4 + xo];
        float4 x8 = x4[(size_t)q7.x * STR4 + xo];
        float v0 = nvd[q0.y], v1 = nvd[q1.y], v2 = nvd[q2.y], v3 = nvd[q3.y];
        float v4 = nvd[q4.y], v5 = nvd[q5.y], v6 = nvd[q6.y], v7 = nvd[q7.y];
        a[0] = fma4(v0, x0, a[0]);
        a[1] = fma4(v1, x1, a[1]);
        a[2] = fma4(v2, x2, a[2]);
        a[3] = fma4(v3, x3, a[3]);
        a[0] = fma4(v4, x5, a[0]);
        a[1] = fma4(v5, x6, a[1]);
        a[2] = fma4(v6, x7, a[2]);
        a[3] = fma4(v7, x8, a[3]);
    }
    for (; j + 4 <= p1; j += 4) {
        int2 q0 = ec[j], q1 = ec[j+1], q2 = ec[j+2], q3 = ec[j+3];
        float v0 = nvd[q0.y], v1 = nvd[q1.y], v2 = nvd[q2.y], v3 = nvd[q3.y];
        a[0] = fma4(v0, x4[(size_t)q0.x * STR4 + xo], a[0]);
        a[1] = fma4(v1, x4[(size_t)q1.x * STR4 + xo], a[1]);
        a[2] = fma4(v2, x4[(size_t)q2.x * STR4 + xo], a[2]);
        a[3] = fma4(v3, x4[(size_t)q3.x * STR4 + xo], a[3]);
    }
    for (; j < p1; j++) {
        int2 q = ec[j];
        a[0] = fma4(nvd[q.y], x4[(size_t)q.x * STR4 + xo], a[0]);
    }
}

// ---------- gen SpMM fused with node scores (emb never materialized) ----------
__global__ __launch_bounds__(256) void spmm64_scores(
    const int* __restrict__ rp_d, const int2* __restrict__ e1, const int2* __restrict__ e2,
    const float* __restrict__ Pg, const float* __restrict__ Wm1,
    const float* __restrict__ Wm2, float* __restrict__ sb)
{
    int y = blockIdx.y;
    const int* rp = rp_d + y * (NN + 1);
    const int2* arr = y ? e2 : e1;
    int row = blockIdx.x * 16 + threadIdx.x / 16;
    int o = threadIdx.x % 16;
    if (row >= NN) return;
    float4 a[4] = {};
    gath_dir_f32<32>(rp, arr, row, (const float4*)Pg, y * 16 + o, a);
    float4 r;
    r.x = fmaxf((a[0].x + a[1].x) + (a[2].x + a[3].x), 0.f);
    r.y = fmaxf((a[0].y + a[1].y) + (a[2].y + a[3].y), 0.f);
    r.z = fmaxf((a[0].z + a[1].z) + (a[2].z + a[3].z), 0.f);
    r.w = fmaxf((a[0].w + a[1].w) + (a[2].w + a[3].w), 0.f);
    const float* Wmh = (y ? Wm2 : Wm1) + GH;  // second half (sa & bm cancel)
    float part = r.x * Wmh[o * 4] + r.y * Wmh[o * 4 + 1]
               + r.z * Wmh[o * 4 + 2] + r.w * Wmh[o * 4 + 3];
    part += __shfl_xor(part, 1); part += __shfl_xor(part, 2);
    part += __shfl_xor(part, 4); part += __shfl_xor(part, 8);
    if (o == 0) sb[y * NN + row] = part;
}

// ---------- softmax epilogue over 16 values held 4-per-lane (4-lane groups) ----------
__device__ __forceinline__ void softmax16_epi(
    float4 r, int node, float* __restrict__ logits, float* __restrict__ wout)
{
    int o = threadIdx.x & 3;
    float mx = fmaxf(fmaxf(r.x, r.y), fmaxf(r.z, r.w));
    mx = fmaxf(mx, __shfl_xor(mx, 1));
    mx = fmaxf(mx, __shfl_xor(mx, 2));
    float e0 = expf(r.x - mx), e1 = expf(r.y - mx), e2 = expf(r.z - mx), e3 = expf(r.w - mx);
    float s = (e0 + e1) + (e2 + e3);
    s += __shfl_xor(s, 1);
    s += __shfl_xor(s, 2);
    float inv = 1.f / s;
    float p0 = e0 * inv, p1 = e1 * inv, p2 = e2 * inv, p3 = e3 * inv;
    float4 lg;
    lg.x = logf(p0 + EPSc); lg.y = logf(p1 + EPSc);
    lg.z = logf(p2 + EPSc); lg.w = logf(p3 + EPSc);
    ((float4*)logits)[(size_t)node * 4 + o] = lg;
    if (wout) {
        // local top2 of 4
        float f = p0, se = -1.f;
        if (p1 > f) { se = f; f = p1; } else se = p1;
        if (p2 > f) { se = f; f = p2; } else if (p2 > se) se = p2;
        if (p3 > f) { se = f; f = p3; } else if (p3 > se) se = p3;
        // merge across lanes
#pragma unroll
        for (int d = 1; d <= 2; d <<= 1) {
            float of = __shfl_xor(f, d), os = __shfl_xor(se, d);
            if (of > f) { se = fmaxf(f, os); f = of; }
            else se = fmaxf(se, of);
        }
        if (o == 0)
            wout[node] = expf(0.5f * logf(f + EPSc) + 0.5f * logf(f - se + EPSc));
    }
}

// ---------- spmm16 + softmax (branches 0/1): logits + w12 ----------
__global__ __launch_bounds__(256) void spmm16_softmax_pair(
    const int* __restrict__ rp_d, const int* __restrict__ rp_c,
    const int2* __restrict__ ed1, const int2* __restrict__ ec1, const float* __restrict__ nvd1,
    const int2* __restrict__ ed2, const int2* __restrict__ ec2, const float* __restrict__ nvd2,
    const float* __restrict__ R01, float* __restrict__ logits_base, float* __restrict__ w12)
{
    int y = blockIdx.y;
    const int* rpd = rp_d + y * (NN + 1);
    const int* rpc = rp_c + y * (NN + 1);
    const int2* ed = y ? ed2 : ed1;
    const int2* ec = y ? ec2 : ec1;
    const float* nvd = y ? nvd2 : nvd1;
    int row = blockIdx.x * 64 + threadIdx.x / 4;
    int o = threadIdx.x % 4;
    if (row >= NN) return;
    const float4* x4 = (const float4*)(R01 + (size_t)y * NN * 16);
    float4 a[4] = {};
    gath_dir_f32<4>(rpd, ed, row, x4, o, a);
    gath_csc_f32<4>(rpc, ec, nvd, row, x4, o, a);
    float4 r;
    r.x = (a[0].x + a[1].x) + (a[2].x + a[3].x);
    r.y = (a[0].y + a[1].y) + (a[2].y + a[3].y);
    r.z = (a[0].z + a[1].z) + (a[2].z + a[3].z);
    r.w = (a[0].w + a[1].w) + (a[2].w + a[3].w);
    softmax16_epi(r, row, logits_base + (size_t)y * NN * NCLS, w12 + (size_t)y * NN);
}

// ---------- spmm16 fused graph + softmax (branch 2): logits_v ----------
__global__ __launch_bounds__(256) void spmm16_fused_softmax(
    const int* __restrict__ rp_d, const int* __restrict__ rp_c,
    const int2* __restrict__ ed1, const int2* __restrict__ ec1, const float* __restrict__ nvd1,
    const int2* __restrict__ ed2, const int2* __restrict__ ec2, const float* __restrict__ nvd2,
    const float* __restrict__ w12, const float* __restrict__ x, float* __restrict__ logits)
{
    int row = blockIdx.x * 64 + threadIdx.x / 4;
    int o = threadIdx.x % 4;
    if (row >= NN) return;
    const float4* x4 = (const float4*)x;
    float4 a[4] = {};
    gath_dir_f32<4>(rp_d, ed1, row, x4, o, a);
    gath_csc_f32<4>(rp_c, ec1, nvd1, row, x4, o, a);
    float4 s1;
    s1.x = (a[0].x + a[1].x) + (a[2].x + a[3].x);
    s1.y = (a[0].y + a[1].y) + (a[2].y + a[3].y);
    s1.z = (a[0].z + a[1].z) + (a[2].z + a[3].z);
    s1.w = (a[0].w + a[1].w) + (a[2].w + a[3].w);
    float4 b[4] = {};
    gath_dir_f32<4>(rp_d + (NN + 1), ed2, row, x4, o, b);
    gath_csc_f32<4>(rp_c + (NN + 1), ec2, nvd2, row, x4, o, b);
    float4 s2;
    s2.x = (b[0].x + b[1].x) + (b[2].x + b[3].x);
    s2.y = (b[0].y + b[1].y) + (b[2].y + b[3].y);
    s2.z = (b[0].z + b[1].z) + (b[2].z + b[3].z);
    s2.w = (b[0].w + b[1].w) + (b[2].w + b[3].w);
    float wa = w12[row], wb = w12[NN + row];
    float inv = 1.f / (wa + wb);
    float w1 = wa * inv, w2 = wb * inv;
    float4 r;
    r.x = w1 * s1.x + w2 * s2.x;
    r.y = w1 * s1.y + w2 * s2.y;
    r.z = w1 * s1.z + w2 * s2.z;
    r.w = w1 * s1.w + w2 * s2.w;
    softmax16_epi(r, row, logits, nullptr);
}

// ---------- bf16 gather helpers (8-deep) ----------
__device__ __forceinline__ void gath_dir_b16(
    const int* __restrict__ rp, const int2* __restrict__ ed, int row,
    const unsigned short* __restrict__ X, int xstride, int o, float* acc)
{
    int p0 = rp[row], p1 = rp[row + 1];
    int j = p0;
    for (; j + 8 <= p1; j += 8) {
        int2 q[8]; short8 x[8];
#pragma unroll
        for (int e = 0; e < 8; e++) q[e] = ed[j + e];
#pragma unroll
        for (int e = 0; e < 8; e++)
            x[e] = *(const short8*)&X[(size_t)q[e].x * xstride + o * 8];
#pragma unroll
        for (int e = 0; e < 8; e++) {
            float v = __int_as_float(q[e].y);
#pragma unroll
            for (int k = 0; k < 8; k++)
                acc[k] = fmaf(v, bf2f((unsigned short)x[e][k]), acc[k]);
        }
    }
    for (; j + 4 <= p1; j += 4) {
        int2 q0 = ed[j], q1 = ed[j+1], q2 = ed[j+2], q3 = ed[j+3];
        short8 x0 = *(const short8*)&X[(size_t)q0.x * xstride + o * 8];
        short8 x1 = *(const short8*)&X[(size_t)q1.x * xstride + o * 8];
        short8 x2 = *(const short8*)&X[(size_t)q2.x * xstride + o * 8];
        short8 x3 = *(const short8*)&X[(size_t)q3.x * xstride + o * 8];
        float v0 = __int_as_float(q0.y), v1 = __int_as_float(q1.y);
        float v2 = __int_as_float(q2.y), v3 = __int_as_float(q3.y);
#pragma unroll
        for (int k = 0; k < 8; k++) {
            acc[k] = fmaf(v0, bf2f((unsigned short)x0[k]), acc[k]);
            acc[k] = fmaf(v1, bf2f((unsigned short)x1[k]), acc[k]);
            acc[k] = fmaf(v2, bf2f((unsigned short)x2[k]), acc[k]);
            acc[k] = fmaf(v3, bf2f((unsigned short)x3[k]), acc[k]);
        }
    }
    for (; j < p1; j++) {
        int2 q = ed[j];
        short8 xv = *(const short8*)&X[(size_t)q.x * xstride + o * 8];
        float v = __int_as_float(q.y);
#pragma unroll
        for (int k = 0; k < 8; k++)
            acc[k] = fmaf(v, bf2f((unsigned short)xv[k]), acc[k]);
    }
}
__device__ __forceinline__ void gath_csc_b16(
    const int* __restrict__ rp, const int2* __restrict__ ec, const float* __restrict__ nvd,
    int row, const unsigned short* __restrict__ X, int xstride, int o, float* acc)
{
    int p0 = rp[row], p1 = rp[row + 1];
    int j = p0;
    for (; j + 8 <= p1; j += 8) {
        int2 q[8]; short8 x[8];
#pragma unroll
        for (int e = 0; e < 8; e++) q[e] = ec[j + e];
#pragma unroll
        for (int e = 0; e < 8; e++)
            x[e] = *(const short8*)&X[(size_t)q[e].x * xstride + o * 8];
        float v[8];
#pragma unroll
        for (int e = 0; e < 8; e++) v[e] = nvd[q[e].y];
#pragma unroll
        for (int e = 0; e < 8; e++) {
#pragma unroll
            for (int k = 0; k < 8; k++)
                acc[k] = fmaf(v[e], bf2f((unsigned short)x[e][k]), acc[k]);
        }
    }
    for (; j + 4 <= p1; j += 4) {
        int2 q0 = ec[j], q1 = ec[j+1], q2 = ec[j+2], q3 = ec[j+3];
        short8 x0 = *(const short8*)&X[(size_t)q0.x * xstride + o * 8];
        short8 x1 = *(const short8*)&X[(size_t)q1.x * xstride + o * 8];
        short8 x2 = *(const short8*)&X[(size_t)q2.x * xstride + o * 8];
        short8 x3 = *(const short8*)&X[(size_t)q3.x * xstride + o * 8];
        float v0 = nvd[q0.y], v1 = nvd[q1.y], v2 = nvd[q2.y], v3 = nvd[q3.y];
#pragma unroll
        for (int k = 0; k < 8; k++) {
            acc[k] = fmaf(v0, bf2f((unsigned short)x0[k]), acc[k]);
            acc[k] = fmaf(v1, bf2f((unsigned short)x1[k]), acc[k]);
            acc[k] = fmaf(v2, bf2f((unsigned short)x2[k]), acc[k]);
            acc[k] = fmaf(v3, bf2f((unsigned short)x3[k]), acc[k]);
        }
    }
    for (; j < p1; j++) {
        int2 q = ec[j];
        short8 xv = *(const short8*)&X[(size_t)q.x * xstride + o * 8];
        float v = nvd[q.y];
#pragma unroll
        for (int k = 0; k < 8; k++)
            acc[k] = fmaf(v, bf2f((unsigned short)xv[k]), acc[k]);
    }
}

// ---------- rows (MI) body, y=1,2 only ----------
__device__ __forceinline__ void rows_b16_body(
    int bx, int y, const int* __restrict__ rp_d, const int* __restrict__ rp_c,
    const int2* __restrict__ ed1, const int2* __restrict__ ec1, const float* __restrict__ nvd1,
    const int2* __restrict__ ed2, const int2* __restrict__ ec2, const float* __restrict__ nvd2,
    const int* __restrict__ rows,
    const unsigned short* __restrict__ Pmi, float* __restrict__ zQ)
{
    int ri = bx * 16 + threadIdx.x / 16;
    int o = threadIdx.x % 16;
    if (ri >= BT) return;
    int node = rows[ri];
    int xoff = (y == 1) ? 128 : 256;
    const unsigned short* X = Pmi + xoff;
    float acc[8] = {};
    if (y == 1) {
        gath_dir_b16(rp_d, ed1, node, X, 384, o, acc);
        gath_csc_b16(rp_c, ec1, nvd1, node, X, 384, o, acc);
    } else {
        gath_dir_b16(rp_d + (NN + 1), ed2, node, X, 384, o, acc);
        gath_csc_b16(rp_c + (NN + 1), ec2, nvd2, node, X, 384, o, acc);
    }
    float* out = zQ + ((size_t)y * BT + ri) * 128 + o * 8;
#pragma unroll
    for (int k = 0; k < 8; k++) out[k] = fmaxf(acc[k], 0.f);
}

// ---------- rows y=0: raw per-view gathers (no w12 dependency) ----------
__device__ __forceinline__ void rows0_gather_body(
    int bx, const int* __restrict__ rp_d, const int* __restrict__ rp_c,
    const int2* __restrict__ ed1, const int2* __restrict__ ec1, const float* __restrict__ nvd1,
    const int2* __restrict__ ed2, const int2* __restrict__ ec2, const float* __restrict__ nvd2,
    const int* __restrict__ rows, const unsigned short* __restrict__ Pmi,
    float* __restrict__ G1, float* __restrict__ G2)
{
    int ri = bx * 16 + threadIdx.x / 16;
    int o = threadIdx.x % 16;
    if (ri >= BT) return;
    int node = rows[ri];
    float g1[8] = {}, g2[8] = {};
    gath_dir_b16(rp_d, ed1, node, Pmi, 384, o, g1);
    gath_csc_b16(rp_c, ec1, nvd1, node, Pmi, 384, o, g1);
    gath_dir_b16(rp_d + (NN + 1), ed2, node, Pmi, 384, o, g2);
    gath_csc_b16(rp_c + (NN + 1), ec2, nvd2, node, Pmi, 384, o, g2);
    float* o1 = G1 + (size_t)ri * 128 + o * 8;
    float* o2 = G2 + (size_t)ri * 128 + o * 8;
    *(float4*)&o1[0] = make_float4(g1[0], g1[1], g1[2], g1[3]);
    *(float4*)&o1[4] = make_float4(g1[4], g1[5], g1[6], g1[7]);
    *(float4*)&o2[0] = make_float4(g2[0], g2[1], g2[2], g2[3]);
    *(float4*)&o2[4] = make_float4(g2[4], g2[5], g2[6], g2[7]);
}

// ---------- branch2: raw per-view gathers over Ph2 (no w12 dependency) ----------
__device__ __forceinline__ void b2gather_body(
    int bx, const int* __restrict__ rp_d, const int* __restrict__ rp_c,
    const int2* __restrict__ ed1, const int2* __restrict__ ec1, const float* __restrict__ nvd1,
    const int2* __restrict__ ed2, const int2* __restrict__ ec2, const float* __restrict__ nvd2,
    const unsigned short* __restrict__ Ph2,
    float* __restrict__ A1, float* __restrict__ A2)
{
    int r = threadIdx.x / 16;
    int o = threadIdx.x % 16;
    int row = bx * 16 + r;
    if (row >= NN) return;
    float a1[8] = {}, a2[8] = {};
    gath_dir_b16(rp_d, ed1, row, Ph2, 128, o, a1);
    gath_csc_b16(rp_c, ec1, nvd1, row, Ph2, 128, o, a1);
    gath_dir_b16(rp_d + (NN + 1), ed2, row, Ph2, 128, o, a2);
    gath_csc_b16(rp_c + (NN + 1), ec2, nvd2, row, Ph2, 128, o, a2);
    float* o1 = A1 + (size_t)row * 128 + o * 8;
    float* o2 = A2 + (size_t)row * 128 + o * 8;
    *(float4*)&o1[0] = make_float4(a1[0], a1[1], a1[2], a1[3]);
    *(float4*)&o1[4] = make_float4(a1[4], a1[5], a1[6], a1[7]);
    *(float4*)&o2[0] = make_float4(a2[0], a2[1], a2[2], a2[3]);
    *(float4*)&o2[4] = make_float4(a2[4], a2[5], a2[6], a2[7]);
}

// ---------- spmm128 fp32 + fused L2 ----------
__device__ __forceinline__ void spmm128f_body(
    float* sm, int bx, int y, const int* __restrict__ rp_d, const int* __restrict__ rp_c,
    const int2* __restrict__ ed, const int2* __restrict__ ec, const float* __restrict__ nvd,
    const float* __restrict__ P01, const float* __restrict__ W2, float* __restrict__ R01)
{
    float* W2s = sm;            // 2048
    float* Qs  = sm + 2048;     // 8*128
    for (int i = threadIdx.x; i < 2048; i += 256) W2s[i] = W2[i];
    int r = threadIdx.x / 32;
    int o = threadIdx.x % 32;
    int row = bx * 8 + r;
    float4 a[4] = {};
    if (row < NN) {
        gath_dir_f32<64>(rp_d + y * (NN + 1), ed, row, (const float4*)P01, y * 32 + o, a);
        gath_csc_f32<64>(rp_c + y * (NN + 1), ec, nvd, row, (const float4*)P01, y * 32 + o, a);
    }
    float4 q;
    q.x = fmaxf((a[0].x + a[1].x) + (a[2].x + a[3].x), 0.f);
    q.y = fmaxf((a[0].y + a[1].y) + (a[2].y + a[3].y), 0.f);
    q.z = fmaxf((a[0].z + a[1].z) + (a[2].z + a[3].z), 0.f);
    q.w = fmaxf((a[0].w + a[1].w) + (a[2].w + a[3].w), 0.f);
    *(float4*)&Qs[r * 128 + o * 4] = q;
    __syncthreads();
    int t = threadIdx.x;
    if (t < 128) {
        int rr = t >> 4, c = t & 15;
        int grow = bx * 8 + rr;
        if (grow < NN) {
            float acc = 0.f;
            const float* qrow = &Qs[rr * 128];
#pragma unroll 8
            for (int k = 0; k < 128; k++)
                acc = fmaf(qrow[k], W2s[k * 16 + c], acc);
            R01[((size_t)y * NN + grow) * 16 + c] = acc;
        }
    }
}

// ---------- mega23: spmm128f (y=0,1) || rows y=1,2 || rows0-gather || b2-gather ----------
// 3:1 interleave: r=b&3==3 -> "other" stream (b2/rows), else spmm stream.
__global__ __launch_bounds__(256) void mega23(
    const int* __restrict__ rp_d, const int* __restrict__ rp_c,
    const int2* __restrict__ ed1, const int2* __restrict__ ec1, const float* __restrict__ nvd1,
    const int2* __restrict__ ed2, const int2* __restrict__ ec2, const float* __restrict__ nvd2,
    const float* __restrict__ P01, const float* __restrict__ W2v1, const float* __restrict__ W2v2,
    float* __restrict__ R01,
    const int* __restrict__ rows, const unsigned short* __restrict__ Pmi,
    float* __restrict__ zQ,
    const unsigned short* __restrict__ Ph2,
    float* __restrict__ A1, float* __restrict__ A2,
    float* __restrict__ G1, float* __restrict__ G2)
{
    __shared__ float sm[2048 + 8 * 128];
    int b = blockIdx.x;
    int u = b >> 2, r = b & 3;
    if (r == 3) {
        if (u < SPB16) {
            b2gather_body(u, rp_d, rp_c, ed1, ec1, nvd1, ed2, ec2, nvd2, Ph2, A1, A2);
            return;
        }
        u -= SPB16;
        if (u < 2 * RBc) {
            int y = 1 + u / RBc;
            rows_b16_body(u % RBc, y, rp_d, rp_c, ed1, ec1, nvd1, ed2, ec2, nvd2,
                          rows, Pmi, zQ);
            return;
        }
        u -= 2 * RBc;
        rows0_gather_body(u, rp_d, rp_c, ed1, ec1, nvd1, ed2, ec2, nvd2,
                          rows, Pmi, G1, G2);
        return;
    }
    int s = u * 3 + r;
    if (s >= 2 * SPB8) return;
    int y = s / SPB8;
    spmm128f_body(sm, s % SPB8, y, rp_d, rp_c, y ? ed2 : ed1, y ? ec2 : ec1,
                  y ? nvd2 : nvd1, P01, y ? W2v2 : W2v1, R01);
}

// ---------- combineB2: w12-weighted combine + relu (+W2 GEMM for branch2) ----------
__global__ __launch_bounds__(256) void combineB2(
    const float* __restrict__ w12,
    const float* __restrict__ A1, const float* __restrict__ A2,
    const float* __restrict__ W2v, float* __restrict__ R2,
    const int* __restrict__ rows,
    const float* __restrict__ G1, const float* __restrict__ G2,
    float* __restrict__ zQ)
{
    __shared__ float sm[2048 + 16 * 128];
    int b = blockIdx.x;
    int r = threadIdx.x / 16;
    int o = threadIdx.x % 16;
    if (b < SPB16) {
        float* W2s = sm;
        float* Qs  = sm + 2048;
        for (int i = threadIdx.x; i < 2048; i += 256) W2s[i] = W2v[i];
        int row = b * 16 + r;
        float wa = w12[row], wb = w12[NN + row];
        float inv = 1.f / (wa + wb);
        float w1 = wa * inv, w2 = wb * inv;
        const float* p1 = A1 + (size_t)row * 128 + o * 8;
        const float* p2 = A2 + (size_t)row * 128 + o * 8;
#pragma unroll
        for (int k = 0; k < 8; k++)
            Qs[r * 128 + o * 8 + k] = fmaxf(w1 * p1[k] + w2 * p2[k], 0.f);
        __syncthreads();
        int t = threadIdx.x;
        int rr = t >> 4, c = t & 15;
        int grow = b * 16 + rr;
        float acc = 0.f;
        const float* qrow = &Qs[rr * 128];
#pragma unroll 8
        for (int k = 0; k < 128; k++)
            acc = fmaf(qrow[k], W2s[k * 16 + c], acc);
        R2[(size_t)grow * 16 + c] = acc;
        return;
    }
    b -= SPB16;
    int ri = b * 16 + r;
    if (ri >= BT) return;
    int node = rows[ri];
    float wa = w12[node], wb = w12[NN + node];
    float inv = 1.f / (wa + wb);
    float w1 = wa * inv, w2 = wb * inv;
    const float* p1 = G1 + (size_t)ri * 128 + o * 8;
    const float* p2 = G2 + (size_t)ri * 128 + o * 8;
    float* out = zQ + (size_t)ri * 128 + o * 8;
#pragma unroll
    for (int k = 0; k < 8; k++)
        out[k] = fmaxf(w1 * p1[k] + w2 * p2[k], 0.f);
}

// ---------- projection head + L2-normalize, bf16 out (8 rows/block, W amortized) ----------
__global__ __launch_bounds__(256) void proj_norm8(
    const float* __restrict__ zQ,
    const float* __restrict__ Wp1, const float* __restrict__ bp1,
    const float* __restrict__ Wp2, const float* __restrict__ bp2,
    unsigned short* __restrict__ z16)
{
    __shared__ float g[8 * MH], u[8 * MH];
    __shared__ float red[4][4];
    int t = threadIdx.x;
    size_t base = (size_t)blockIdx.y * BT + (size_t)blockIdx.x * 8;
    for (int idx = t; idx < 8 * MH; idx += 256)
        g[idx] = zQ[(base + (idx >> 7)) * MH + (idx & 127)];
    __syncthreads();
    int col = t & 127;
    int rh = t >> 7;               // 0 or 1: rows rh*4 .. rh*4+3
    float acc[4];
    float b1 = bp1[col];
#pragma unroll
    for (int rr = 0; rr < 4; rr++) acc[rr] = b1;
    for (int k = 0; k < MH; k++) {
        float wk = Wp1[k * MH + col];
#pragma unroll
        for (int rr = 0; rr < 4; rr++)
            acc[rr] = fmaf(g[(rh * 4 + rr) * MH + k], wk, acc[rr]);
    }
#pragma unroll
    for (int rr = 0; rr < 4; rr++)
        u[(rh * 4 + rr) * MH + col] = acc[rr] > 0.f ? acc[rr] : (expf(acc[rr]) - 1.f);
    __syncthreads();
    float z[4];
    float b2 = bp2[col];
#pragma unroll
    for (int rr = 0; rr < 4; rr++) z[rr] = b2;
    for (int k = 0; k < MH; k++) {
        float wk = Wp2[k * MH + col];
#pragma unroll
        for (int rr = 0; rr < 4; rr++)
            z[rr] = fmaf(u[(rh * 4 + rr) * MH + k], wk, z[rr]);
    }
    float sq[4];
#pragma unroll
    for (int rr = 0; rr < 4; rr++) sq[rr] = z[rr] * z[rr];
#pragma unroll
    for (int off = 32; off; off >>= 1) {
#pragma unroll
        for (int rr = 0; rr < 4; rr++) sq[rr] += __shfl_xor(sq[rr], off);
    }
    int w = t >> 6;
    if ((t & 63) == 0) {
#pragma unroll
        for (int rr = 0; rr < 4; rr++) red[w][rr] = sq[rr];
    }
    __syncthreads();
#pragma unroll
    for (int rr = 0; rr < 4; rr++) {
        float nrm = sqrtf(red[rh * 2][rr] + red[rh * 2 + 1][rr]);
        z16[(base + rh * 4 + rr) * MH + col] = f2bf(z[rr] / nrm);
    }
}

__global__ void contrast_reduce(const float* __restrict__ stats, float* __restrict__ out3)
{
    int p = blockIdx.x, t = threadIdx.x;
    const float* diag = stats + (size_t)p * 3 * BT;
    const float* rs = diag + BT;
    const float* cs = rs + BT;
    float s1 = 0.f, s2 = 0.f;
    for (int i = t; i < BT; i += 256) {
        float d = diag[i];
        s1 += logf(d / (rs[i] + EPSc) + EPSc);
        s2 += logf(d / (cs[i] + EPSc) + EPSc);
    }
#pragma unroll
    for (int off = 32; off; off >>= 1) { s1 += __shfl_down(s1, off); s2 += __shfl_down(s2, off); }
    __shared__ float sh[8];
    if ((t & 63) == 0) { sh[(t >> 6) * 2] = s1; sh[(t >> 6) * 2 + 1] = s2; }
    __syncthreads();
    if (t == 0) {
        float a = sh[0] + sh[2] + sh[4] + sh[6];
        float b = sh[1] + sh[3] + sh[5] + sh[7];
        out3[p] = 0.5f * (-a / BT - b / BT);
    }
}

// ---------- host ----------
extern "C" void kernel_launch(void* const* d_in, const int* in_sizes, int n_in,
                              void* d_out, int out_size, void* d_ws, size_t ws_size,
                              hipStream_t stream)
{
    const float* feat   = (const float*)d_in[0];
    const int*   ind1   = (const int*)d_in[1];
    const float* vals1  = (const float*)d_in[2];
    const int*   ind2   = (const int*)d_in[3];
    const float* vals2  = (const float*)d_in[4];
    const int*   idxb   = (const int*)d_in[5];
    const float* Wm1    = (const float*)d_in[7];
    const float* Wm2    = (const float*)d_in[10];
    const float* W2_v1  = (const float*)d_in[13];
    const float* W2_v2  = (const float*)d_in[15];
    const float* W2_v   = (const float*)d_in[17];
    const float* Wp1    = (const float*)d_in[21];
    const float* bp1    = (const float*)d_in[22];
    const float* Wp2    = (const float*)d_in[23];
    const float* bp2    = (const float*)d_in[24];
    float* dout = (float*)d_out;

    float* ws = (float*)d_ws;
    size_t off = 0;
    auto alloc = [&](size_t n) { n = (n + 3) & ~(size_t)3; float* p = ws + off; off += n; return p; };
    auto alloc_s = [&](size_t n) { return (unsigned short*)alloc((n + 1) / 2); };

    // --- shared pool ---
    float* pool = alloc(16000000);
    float* Pg   = pool;                      // [0, 3.84M)  (dead after spmm64_scores)
    float* P01  = pool + 3840000;            // [3.84M, 11.52M)  [NN][256] f32
    float* R01  = pool + 11520000;           // [11.52M, 12.48M)
    float* zQ   = pool + 12480000;           // [12.48M, 14.05M)
    float* A1   = pool;                      // overlays Pg: [NN][128] f32, written in mega23
    float* G1   = pool + 14052864;           // [BT][128] f32
    float* G2   = pool + 14577152;           // [BT][128] f32
    float* R2   = pool + 15101440;           // [NN][16] f32

    // --- persistent ---
    unsigned short* feat_hi = alloc_s((size_t)NN * FD);
    unsigned short* feat_lo = alloc_s((size_t)NN * FD);
    float* A2 = (float*)feat_hi;             // feat splits dead after mega1; 3.84M floats exactly
    unsigned short* Ph2d    = alloc_s((size_t)NN * CH);
    unsigned short* Pmi16d  = alloc_s((size_t)NN * 384);
    float* sb   = alloc(2 * NN);
    float* w12  = alloc(2 * NN);
    float* stats = alloc((size_t)3 * 3 * BT);
    unsigned short* z16 = alloc_s((size_t)3 * BT * MH);
    int2* ed1 = (int2*)alloc(2 * (size_t)EE);
    int2* ed2 = (int2*)alloc(2 * (size_t)EE);
    int2* ec1 = (int2*)alloc(2 * (size_t)EE);
    int2* ec2 = (int2*)alloc(2 * (size_t)EE);
    float* nvd1 = alloc(EE);
    float* nvd2 = alloc(EE);
    int* sd1 = (int*)alloc(EE);
    int* sd2 = (int*)alloc(EE);
    int* sc1 = (int*)alloc(EE);
    int* sc2 = (int*)alloc(EE);
    int* rp4  = (int*)alloc(4 * (NN + 1));
    int* cnt4 = (int*)alloc(4 * NN);
    int* bsum = (int*)alloc(128);
    int* rp_d = rp4;
    int* rp_c = rp4 + 2 * (NN + 1);
    // weights (bf16 splits for K=256 GEMMs)
    unsigned short* wgen12h = alloc_s(32768); unsigned short* wgen12l = alloc_s(32768);
    unsigned short* w1pairh = alloc_s(65536); unsigned short* w1pairl = alloc_s(65536);
    unsigned short* w1vh    = alloc_s(32768); unsigned short* w1vl    = alloc_s(32768);
    unsigned short* wgallh  = alloc_s(98304); unsigned short* wgalll  = alloc_s(98304);

    const int NB = (NN + 1 + 1023) / 1024;
    const int NCNT = (EE + 255) / 256;

    // ---- prep ----
    hipMemsetAsync(cnt4, 0, 4 * NN * 4, stream);
    split_bf16<<<((long)NN * FD + 255) / 256, 256, 0, stream>>>(feat, feat_hi, feat_lo, (long)NN * FD);
    {
        WSArgs a;
        a.s[0] = (const float*)d_in[6];  a.h[0] = wgen12h;          a.l[0] = wgen12l;
        a.s[1] = (const float*)d_in[9];  a.h[1] = wgen12h + 16384;  a.l[1] = wgen12l + 16384;
        a.s[2] = (const float*)d_in[12]; a.h[2] = w1pairh;          a.l[2] = w1pairl;
        a.s[3] = (const float*)d_in[14]; a.h[3] = w1pairh + 32768;  a.l[3] = w1pairl + 32768;
        a.s[4] = (const float*)d_in[16]; a.h[4] = w1vh;             a.l[4] = w1vl;
        a.s[5] = (const float*)d_in[18]; a.h[5] = wgallh;           a.l[5] = wgalll;
        a.s[6] = (const float*)d_in[19]; a.h[6] = wgallh + 32768;   a.l[6] = wgalll + 32768;
        a.s[7] = (const float*)d_in[20]; a.h[7] = wgallh + 65536;   a.l[7] = wgalll + 65536;
        wsplit_all<<<(229376 + 255) / 256, 256, 0, stream>>>(a);
    }

    // ---- mega0: count(+seq) || Ph2 gemm1 || Pmi gemm1×3 ----
    mega0<<<4 * GBc + NCNT, 256, 0, stream>>>(ind1, ind2, cnt4, sd1, sd2, sc1, sc2,
                                              feat_hi, w1vh, Ph2d, wgallh, Pmi16d);

    // ---- scans ----
    scan_block4<<<dim3(NB, 4), 1024, 0, stream>>>(cnt4, rp4, bsum);
    scan_bsum4<<<4, 64, 0, stream>>>(bsum, NB);
    scan_add4<<<dim3(NB, 4), 1024, 0, stream>>>(bsum, rp4);

    // ---- mega1: atomic-free place || Pg gemm3 || P01 gemm3×2 ----
    mega1<<<3 * GBc + NCNT, 256, 0, stream>>>(ind1, vals1, ind2, vals2,
                                              sd1, sd2, sc1, sc2, rp4,
                                              ed1, ec1, ed2, ec2,
                                              feat_hi, feat_lo, wgen12h, wgen12l, Pg,
                                              w1pairh, w1pairl, P01);

    // ---- gen_view: spmm64 fused with node scores, then nv ----
    spmm64_scores<<<dim3((NN + 15) / 16, 2), 256, 0, stream>>>(rp_d, ed1, ed2, Pg, Wm1, Wm2, sb);
    gen_nv<<<dim3((NN + 255) / 256, 2), 256, 0, stream>>>(rp_d, ed1, ed2, sb, nvd1, nvd2);

    // ---- mega23: branch01 spmm+L2 || rows y=1,2 || rows0-gather || branch2-gather ----
    mega23<<<4 * NOX, 256, 0, stream>>>(rp_d, rp_c, ed1, ec1, nvd1,
                                        ed2, ec2, nvd2, P01, W2_v1, W2_v2,
                                        R01, idxb, Pmi16d, zQ,
                                        Ph2d, A1, A2, G1, G2);

    // ---- branches 0/1: layer-2 aggregate + fused softmax + w12 ----
    spmm16_softmax_pair<<<dim3((NN + 63) / 64, 2), 256, 0, stream>>>(
        rp_d, rp_c, ed1, ec1, nvd1, ed2, ec2, nvd2, R01, dout + (size_t)NN * NCLS, w12);

    // ---- combine: branch2 w12-mix + W2 GEMM -> R2 ; rows y=0 mix -> zQ ----
    combineB2<<<SPB16 + RBc, 256, 0, stream>>>(w12, A1, A2, W2_v, R2, idxb, G1, G2, zQ);

    // ---- branch 2: layer-2 aggregate + fused softmax ----
    spmm16_fused_softmax<<<(NN + 63) / 64, 256, 0, stream>>>(
        rp_d, rp_c, ed1, ec1, nvd1, ed2, ec2, nvd2, w12, R2, dout);

    // ---- MI projection + contrast ----
    proj_norm8<<<dim3(BT / 8, 3), 256, 0, stream>>>(zQ, Wp1, bp1, Wp2, bp2, z16);
    hipMemsetAsync(stats, 0, (size_t)3 * 3 * BT * 4, stream);
    contrast_direct<<<dim3(32, 32, 3), 256, 0, stream>>>(z16, stats);
    contrast_reduce<<<3, 256, 0, stream>>>(stats, dout + (size_t)3 * NN * NCLS);
}

// Round 5
// 746.100 us; speedup vs baseline: 1.1839x; 1.1839x over previous
//
#include <hip/hip_runtime.h>
#include <math.h>

#define NN 30000
#define EE 480000
#define FD 256
#define CH 128
#define NCLS 16
#define GH 64
#define MH 128
#define BT 4096
#define EPSc 1e-8f
#define GBc ((NN + 127) / 128)
#define SPB8 ((NN + 7) / 8)
#define SPB16 ((NN + 15) / 16)
#define RBc ((BT + 15) / 16)
#define PRB ((NN + 63) / 64)     // 469 pair blocks per view
#define PJB (BT / 8)             // 512 proj blocks per plane
#define PX4 1056                 // pairX quarter-stride

typedef __attribute__((ext_vector_type(8))) short short8;
typedef __attribute__((ext_vector_type(4))) float f32x4;

// ---------- helpers ----------
__device__ __forceinline__ unsigned short f2bf(float x) {
    unsigned b = __float_as_uint(x);
    unsigned r = b + 0x7FFFu + ((b >> 16) & 1u);
    return (unsigned short)(r >> 16);
}
__device__ __forceinline__ float bf2f(unsigned short h) {
    return __uint_as_float(((unsigned)h) << 16);
}
__device__ __forceinline__ float4 fma4(float s, float4 x, float4 a) {
    a.x = fmaf(s, x.x, a.x); a.y = fmaf(s, x.y, a.y);
    a.z = fmaf(s, x.z, a.z); a.w = fmaf(s, x.w, a.w);
    return a;
}

struct WSArgs {
    const float* s[8];
    unsigned short* h[8];
    unsigned short* l[8];
};

// ---------- prep_all: split_bf16 || wsplit || count ----------
__global__ __launch_bounds__(256) void prep_all(
    const float* __restrict__ feat, unsigned short* __restrict__ fhi,
    unsigned short* __restrict__ flo, WSArgs a,
    const int* __restrict__ i1, const int* __restrict__ i2, int* __restrict__ cnt,
    int* __restrict__ sd1, int* __restrict__ sd2,
    int* __restrict__ sc1, int* __restrict__ sc2)
{
    int b = blockIdx.x;
    if (b < 30000) {
        long i = (long)b * 256 + threadIdx.x;
        float v = feat[i];
        unsigned short h = f2bf(v);
        fhi[i] = h;
        flo[i] = f2bf(v - bf2f(h));
        return;
    }
    b -= 30000;
    if (b < 896) {
        int i = b * 256 + threadIdx.x;
        if (i >= 229376) return;
        constexpr int NNp[8] = {64, 64, 128, 128, 128, 128, 128, 128};
        constexpr int OFF[9] = {0, 16384, 32768, 65536, 98304, 131072, 163840, 196608, 229376};
        int w = 0;
#pragma unroll
        for (int t = 1; t < 8; t++) if (i >= OFF[t]) w = t;
        int j = i - OFF[w];
        int N = NNp[w];
        int k = j / N, n = j % N;
        float v = a.s[w][j];
        unsigned short hh = f2bf(v);
        a.h[w][(size_t)n * 256 + k] = hh;
        a.l[w][(size_t)n * 256 + k] = f2bf(v - bf2f(hh));
        return;
    }
    b -= 896;
    int e = b * 256 + threadIdx.x;
    if (e >= EE) return;
    int r1 = i1[e], c1 = i1[EE + e];
    int r2 = i2[e], c2 = i2[EE + e];
    sd1[e] = atomicAdd(&cnt[r1], 1);
    sd2[e] = atomicAdd(&cnt[NN + r2], 1);
    sc1[e] = atomicAdd(&cnt[2 * NN + c1], 1);
    sc2[e] = atomicAdd(&cnt[3 * NN + c2], 1);
}

// ---------- GEMM bodies ----------
template <int NT, bool OUT16>
__device__ __forceinline__ void gemm3_body(
    unsigned short* sm, int bx,
    const unsigned short* __restrict__ Ahi, const unsigned short* __restrict__ Alo,
    const unsigned short* __restrict__ BThi, const unsigned short* __restrict__ BTlo,
    int K, void* __restrict__ Cv, int Cstride, int M)
{
    unsigned short* Ah = sm;
    unsigned short* Al = Ah + 128 * 40;
    unsigned short* Bh = Al + 128 * 40;
    unsigned short* Bl = Bh + NT * 16 * 40;
    int t = threadIdx.x;
    int w = t >> 6, l = t & 63;
    int lane = l & 15, quad = l >> 4;
    int row0 = bx * 128;
    f32x4 acc[2][NT];
#pragma unroll
    for (int s = 0; s < 2; s++)
#pragma unroll
        for (int n = 0; n < NT; n++) acc[s][n] = (f32x4)(0.f);

    int ar = t >> 1, ako = (t & 1) << 4;
    int nkc = K >> 5;
    for (int kc = 0; kc < nkc; kc++) {
        int kb = kc << 5;
        {
            int gr = row0 + ar;
            float4 h0, h1, l0, l1;
            if (gr < M) {
                const float4* pH = (const float4*)&Ahi[(size_t)gr * K + kb + ako];
                const float4* pL = (const float4*)&Alo[(size_t)gr * K + kb + ako];
                h0 = pH[0]; h1 = pH[1]; l0 = pL[0]; l1 = pL[1];
            } else {
                h0 = h1 = l0 = l1 = make_float4(0.f, 0.f, 0.f, 0.f);
            }
            float4* dH = (float4*)&Ah[ar * 40 + ako];
            dH[0] = h0; dH[1] = h1;
            float4* dL = (float4*)&Al[ar * 40 + ako];
            dL[0] = l0; dL[1] = l1;
        }
        if (ar < NT * 16) {
            const float4* pH = (const float4*)&BThi[(size_t)ar * K + kb + ako];
            const float4* pL = (const float4*)&BTlo[(size_t)ar * K + kb + ako];
            float4 h0 = pH[0], h1 = pH[1], l0 = pL[0], l1 = pL[1];
            float4* dH = (float4*)&Bh[ar * 40 + ako];
            dH[0] = h0; dH[1] = h1;
            float4* dL = (float4*)&Bl[ar * 40 + ako];
            dL[0] = l0; dL[1] = l1;
        }
        __syncthreads();
        short8 aH[2], aL[2];
#pragma unroll
        for (int s = 0; s < 2; s++) {
            int r = w * 32 + s * 16 + lane;
            aH[s] = *(const short8*)&Ah[r * 40 + quad * 8];
            aL[s] = *(const short8*)&Al[r * 40 + quad * 8];
        }
#pragma unroll
        for (int n = 0; n < NT; n++) {
            int r = n * 16 + lane;
            short8 bH = *(const short8*)&Bh[r * 40 + quad * 8];
            short8 bL = *(const short8*)&Bl[r * 40 + quad * 8];
#pragma unroll
            for (int s = 0; s < 2; s++) {
                acc[s][n] = __builtin_amdgcn_mfma_f32_16x16x32_bf16(aH[s], bH, acc[s][n], 0, 0, 0);
                acc[s][n] = __builtin_amdgcn_mfma_f32_16x16x32_bf16(aH[s], bL, acc[s][n], 0, 0, 0);
                acc[s][n] = __builtin_amdgcn_mfma_f32_16x16x32_bf16(aL[s], bH, acc[s][n], 0, 0, 0);
            }
        }
        __syncthreads();
    }
#pragma unroll
    for (int s = 0; s < 2; s++) {
        int rb = row0 + w * 32 + s * 16 + quad * 4;
#pragma unroll
        for (int reg = 0; reg < 4; reg++) {
            int gr = rb + reg;
            if (gr >= M) continue;
#pragma unroll
            for (int n = 0; n < NT; n++) {
                if (OUT16)
                    ((unsigned short*)Cv)[(size_t)gr * Cstride + n * 16 + lane] = f2bf(acc[s][n][reg]);
                else
                    ((float*)Cv)[(size_t)gr * Cstride + n * 16 + lane] = acc[s][n][reg];
            }
        }
    }
}

template <int NT, bool OUT16>
__device__ __forceinline__ void gemm1_body(
    unsigned short* sm, int bx,
    const unsigned short* __restrict__ Ahi,
    const unsigned short* __restrict__ BThi,
    int K, void* __restrict__ Cv, int Cstride, int M)
{
    unsigned short* Ah = sm;
    unsigned short* Bh = Ah + 128 * 40;
    int t = threadIdx.x;
    int w = t >> 6, l = t & 63;
    int lane = l & 15, quad = l >> 4;
    int row0 = bx * 128;
    f32x4 acc[2][NT];
#pragma unroll
    for (int s = 0; s < 2; s++)
#pragma unroll
        for (int n = 0; n < NT; n++) acc[s][n] = (f32x4)(0.f);

    int ar = t >> 1, ako = (t & 1) << 4;
    int nkc = K >> 5;
    for (int kc = 0; kc < nkc; kc++) {
        int kb = kc << 5;
        {
            int gr = row0 + ar;
            float4 h0, h1;
            if (gr < M) {
                const float4* pH = (const float4*)&Ahi[(size_t)gr * K + kb + ako];
                h0 = pH[0]; h1 = pH[1];
            } else {
                h0 = h1 = make_float4(0.f, 0.f, 0.f, 0.f);
            }
            float4* dH = (float4*)&Ah[ar * 40 + ako];
            dH[0] = h0; dH[1] = h1;
        }
        if (ar < NT * 16) {
            const float4* pH = (const float4*)&BThi[(size_t)ar * K + kb + ako];
            float4 h0 = pH[0], h1 = pH[1];
            float4* dH = (float4*)&Bh[ar * 40 + ako];
            dH[0] = h0; dH[1] = h1;
        }
        __syncthreads();
        short8 aH[2];
#pragma unroll
        for (int s = 0; s < 2; s++)
            aH[s] = *(const short8*)&Ah[(w * 32 + s * 16 + lane) * 40 + quad * 8];
#pragma unroll
        for (int n = 0; n < NT; n++) {
            short8 bH = *(const short8*)&Bh[(n * 16 + lane) * 40 + quad * 8];
#pragma unroll
            for (int s = 0; s < 2; s++)
                acc[s][n] = __builtin_amdgcn_mfma_f32_16x16x32_bf16(aH[s], bH, acc[s][n], 0, 0, 0);
        }
        __syncthreads();
    }
#pragma unroll
    for (int s = 0; s < 2; s++) {
        int rb = row0 + w * 32 + s * 16 + quad * 4;
#pragma unroll
        for (int reg = 0; reg < 4; reg++) {
            int gr = rb + reg;
            if (gr >= M) continue;
#pragma unroll
            for (int n = 0; n < NT; n++) {
                if (OUT16)
                    ((unsigned short*)Cv)[(size_t)gr * Cstride + n * 16 + lane] = f2bf(acc[s][n][reg]);
                else
                    ((float*)Cv)[(size_t)gr * Cstride + n * 16 + lane] = acc[s][n][reg];
            }
        }
    }
}

// ---------- mega1x: all GEMMs (Pg, P01x2, Ph2, Pmix3) || atomic-free placement ----------
__global__ __launch_bounds__(256) void mega1x(
    const int* __restrict__ i1, const float* __restrict__ v1,
    const int* __restrict__ i2, const float* __restrict__ v2,
    const int* __restrict__ sd1, const int* __restrict__ sd2,
    const int* __restrict__ sc1, const int* __restrict__ sc2,
    const int* __restrict__ rp4,
    int2* __restrict__ ed1, int2* __restrict__ ec1,
    int2* __restrict__ ed2, int2* __restrict__ ec2,
    const unsigned short* __restrict__ feat_hi, const unsigned short* __restrict__ feat_lo,
    const unsigned short* __restrict__ wgen12h, const unsigned short* __restrict__ wgen12l,
    float* __restrict__ Pg,
    const unsigned short* __restrict__ w1pairh, const unsigned short* __restrict__ w1pairl,
    float* __restrict__ P01,
    const unsigned short* __restrict__ w1vh, unsigned short* __restrict__ Ph2,
    const unsigned short* __restrict__ wgallh, unsigned short* __restrict__ Pmi16)
{
    __shared__ unsigned short sm[128 * 40 * 2 + 8 * 16 * 40 * 2];
    int b = blockIdx.x;
    if (b < GBc) {
        gemm3_body<8, false>(sm, b, feat_hi, feat_lo, wgen12h, wgen12l, FD, Pg, 128, NN);
        return;
    }
    b -= GBc;
    if (b < 2 * GBc) {
        int y = b / GBc, bx = b % GBc;
        gemm3_body<8, false>(sm, bx, feat_hi, feat_lo,
                             w1pairh + (size_t)y * 32768, w1pairl + (size_t)y * 32768,
                             FD, P01 + (size_t)y * 128, 256, NN);
        return;
    }
    b -= 2 * GBc;
    if (b < GBc) {
        gemm1_body<8, true>(sm, b, feat_hi, w1vh, FD, Ph2, 128, NN);
        return;
    }
    b -= GBc;
    if (b < 3 * GBc) {
        int y = b / GBc, bx = b % GBc;
        gemm1_body<8, true>(sm, bx, feat_hi, wgallh + (size_t)y * 32768,
                            FD, Pmi16 + (size_t)y * 128, 384, NN);
        return;
    }
    b -= 3 * GBc;
    int e = b * 256 + threadIdx.x;
    if (e >= EE) return;
    const int* rp_d1 = rp4;
    const int* rp_d2 = rp4 + (NN + 1);
    const int* rp_c1 = rp4 + 2 * (NN + 1);
    const int* rp_c2 = rp4 + 3 * (NN + 1);
    int r = i1[e], c = i1[EE + e];
    int p = rp_d1[r] + sd1[e];
    ed1[p] = make_int2(c, __float_as_int(v1[e]));
    ec1[rp_c1[c] + sc1[e]] = make_int2(r, p);
    r = i2[e]; c = i2[EE + e];
    p = rp_d2[r] + sd2[e];
    ed2[p] = make_int2(c, __float_as_int(v2[e]));
    ec2[rp_c2[c] + sc2[e]] = make_int2(r, p);
}

// ---------- contrast ----------
__global__ __launch_bounds__(256) void contrast_direct(
    const unsigned short* __restrict__ z16, float* __restrict__ stats)
{
    int p = blockIdx.z;
    int pa = (p == 2) ? 1 : 0;
    int pb = (p == 0) ? 1 : 2;
    const unsigned short* A = z16 + (size_t)pa * BT * MH;
    const unsigned short* B = z16 + (size_t)pb * BT * MH;
    float* diag = stats + (size_t)p * 3 * BT;
    float* rs = diag + BT;
    float* cs = rs + BT;
    int t = threadIdx.x;
    int w = t >> 6, l = t & 63, m = l & 15, quad = l >> 4;
    int i0 = blockIdx.y * 128, j0 = blockIdx.x * 128;

    short8 afr[2][4];
#pragma unroll
    for (int s = 0; s < 2; s++) {
        const unsigned short* arow = &A[(size_t)(i0 + w * 32 + s * 16 + m) * MH + quad * 8];
#pragma unroll
        for (int kc = 0; kc < 4; kc++)
            afr[s][kc] = *(const short8*)(arow + kc * 32);
    }
    f32x4 acc[2][8];
#pragma unroll
    for (int s = 0; s < 2; s++)
#pragma unroll
        for (int n = 0; n < 8; n++) acc[s][n] = (f32x4)(0.f);

#pragma unroll
    for (int kc = 0; kc < 4; kc++) {
#pragma unroll
        for (int n = 0; n < 8; n++) {
            short8 bf = *(const short8*)&B[(size_t)(j0 + n * 16 + m) * MH + kc * 32 + quad * 8];
            acc[0][n] = __builtin_amdgcn_mfma_f32_16x16x32_bf16(afr[0][kc], bf, acc[0][n], 0, 0, 0);
            acc[1][n] = __builtin_amdgcn_mfma_f32_16x16x32_bf16(afr[1][kc], bf, acc[1][n], 0, 0, 0);
        }
    }
    float colp[8];
#pragma unroll
    for (int n = 0; n < 8; n++) colp[n] = 0.f;
#pragma unroll
    for (int s = 0; s < 2; s++) {
        int rbase = i0 + w * 32 + s * 16 + quad * 4;
#pragma unroll
        for (int reg = 0; reg < 4; reg++) {
            float rsum = 0.f;
            int gi = rbase + reg;
#pragma unroll
            for (int n = 0; n < 8; n++) {
                float mv = expf(acc[s][n][reg] * 2.0f);
                rsum += mv;
                colp[n] += mv;
                int gj = j0 + n * 16 + m;
                if (gi == gj) diag[gi] = mv;
            }
            rsum += __shfl_xor(rsum, 1); rsum += __shfl_xor(rsum, 2);
            rsum += __shfl_xor(rsum, 4); rsum += __shfl_xor(rsum, 8);
            if (m == 0) atomicAdd(&rs[gi], rsum);
        }
    }
    __shared__ float scol[128];
    if (t < 128) scol[t] = 0.f;
    __syncthreads();
#pragma unroll
    for (int n = 0; n < 8; n++) {
        float v = colp[n];
        v += __shfl_xor(v, 16); v += __shfl_xor(v, 32);
        if (quad == (n & 3)) atomicAdd(&scol[n * 16 + m], v);
    }
    __syncthreads();
    if (t < 128) atomicAdd(&cs[j0 + t], scol[t]);
}

// ---------- scans ----------
__global__ __launch_bounds__(1024) void scan_block4(const int* __restrict__ cnt,
                                                    int* __restrict__ rowptr,
                                                    int* __restrict__ bsum) {
    int y = blockIdx.y;
    int* rp = rowptr + y * (NN + 1);
    int* bs = bsum + y * 32;
    __shared__ int tmp[1024];
    int t = threadIdx.x;
    int i = blockIdx.x * 1024 + t;
    int v = (i < NN) ? cnt[y * NN + i] : 0;
    tmp[t] = v;
    __syncthreads();
    for (int off = 1; off < 1024; off <<= 1) {
        int add = (t >= off) ? tmp[t - off] : 0;
        __syncthreads();
        tmp[t] += add;
        __syncthreads();
    }
    if (i <= NN) rp[i] = tmp[t] - v;
    if (t == 1023) bs[blockIdx.x] = tmp[1023];
}
__global__ void scan_bsum4(int* __restrict__ bsum, int nb) {
    bsum += blockIdx.x * 32;
    int t = threadIdx.x;
    int orig = (t < nb) ? bsum[t] : 0;
    int v = orig;
    for (int off = 1; off < 64; off <<= 1) {
        int u = __shfl_up(v, off);
        if (t >= off) v += u;
    }
    if (t < nb) bsum[t] = v - orig;
}
__global__ void scan_add4(const int* __restrict__ bsum, int* __restrict__ rowptr) {
    int y = blockIdx.y;
    const int* bs = bsum + y * 32;
    int* rp = rowptr + y * (NN + 1);
    int i = blockIdx.x * 1024 + threadIdx.x;
    if (i <= NN) rp[i] += bs[blockIdx.x];
}

// ---------- row-parallel nv ----------
__global__ __launch_bounds__(256) void gen_nv(
    const int* __restrict__ rp_d, int2* __restrict__ ed1, int2* __restrict__ ed2,
    const float* __restrict__ sb, float* __restrict__ nvd1, float* __restrict__ nvd2)
{
    int y = blockIdx.y;
    int row = blockIdx.x * 256 + threadIdx.x;
    if (row >= NN) return;
    const int* rp = rp_d + y * (NN + 1);
    int2* ed = y ? ed2 : ed1;
    float* nvd = y ? nvd2 : nvd1;
    const float* sbv = sb + (size_t)y * NN;
    int p0 = rp[row], p1 = rp[row + 1];
    float m = -3.4e38f, sum = 0.f;
    for (int j = p0; j < p1; j++) {
        float x = sbv[ed[j].x];
        if (x > m) { sum = sum * expf(m - x) + 1.f; m = x; }
        else sum += expf(x - m);
    }
    float inv = 1.f / sum;
    for (int j = p0; j < p1; j++) {
        int2 q = ed[j];
        float nv = __int_as_float(q.y) + 0.5f * expf(sbv[q.x] - m) * inv;
        nvd[j] = nv;
        ed[j].y = __float_as_int(nv);
    }
}

// ---------- fp32 gather helpers (8-deep MLP) ----------
template <int STR4>
__device__ __forceinline__ void gath_dir_f32(
    const int* __restrict__ rp, const int2* __restrict__ ed, int row,
    const float4* __restrict__ x4, int xo, float4* a)
{
    int p0 = rp[row], p1 = rp[row + 1];
    int j = p0;
    for (; j + 8 <= p1; j += 8) {
        int2 q0 = ed[j], q1 = ed[j+1], q2 = ed[j+2], q3 = ed[j+3];
        int2 q4 = ed[j+4], q5 = ed[j+5], q6 = ed[j+6], q7 = ed[j+7];
        float4 x0 = x4[(size_t)q0.x * STR4 + xo];
        float4 x1 = x4[(size_t)q1.x * STR4 + xo];
        float4 x2 = x4[(size_t)q2.x * STR4 + xo];
        float4 x3 = x4[(size_t)q3.x * STR4 + xo];
        float4 x5 = x4[(size_t)q4.x * STR4 + xo];
        float4 x6 = x4[(size_t)q5.x * STR4 + xo];
        float4 x7 = x4[(size_t)q6.x * STR4 + xo];
        float4 x8 = x4[(size_t)q7.x * STR4 + xo];
        a[0] = fma4(__int_as_float(q0.y), x0, a[0]);
        a[1] = fma4(__int_as_float(q1.y), x1, a[1]);
        a[2] = fma4(__int_as_float(q2.y), x2, a[2]);
        a[3] = fma4(__int_as_float(q3.y), x3, a[3]);
        a[0] = fma4(__int_as_float(q4.y), x5, a[0]);
        a[1] = fma4(__int_as_float(q5.y), x6, a[1]);
        a[2] = fma4(__int_as_float(q6.y), x7, a[2]);
        a[3] = fma4(__int_as_float(q7.y), x8, a[3]);
    }
    for (; j + 4 <= p1; j += 4) {
        int2 q0 = ed[j], q1 = ed[j+1], q2 = ed[j+2], q3 = ed[j+3];
        a[0] = fma4(__int_as_float(q0.y), x4[(size_t)q0.x * STR4 + xo], a[0]);
        a[1] = fma4(__int_as_float(q1.y), x4[(size_t)q1.x * STR4 + xo], a[1]);
        a[2] = fma4(__int_as_float(q2.y), x4[(size_t)q2.x * STR4 + xo], a[2]);
        a[3] = fma4(__int_as_float(q3.y), x4[(size_t)q3.x * STR4 + xo], a[3]);
    }
    for (; j < p1; j++) {
        int2 q = ed[j];
        a[0] = fma4(__int_as_float(q.y), x4[(size_t)q.x * STR4 + xo], a[0]);
    }
}
template <int STR4>
__device__ __forceinline__ void gath_csc_f32(
    const int* __restrict__ rp, const int2* __restrict__ ec, const float* __restrict__ nvd,
    int row, const float4* __restrict__ x4, int xo, float4* a)
{
    int p0 = rp[row], p1 = rp[row + 1];
    int j = p0;
    for (; j + 8 <= p1; j += 8) {
        int2 q0 = ec[j], q1 = ec[j+1], q2 = ec[j+2], q3 = ec[j+3];
        int2 q4 = ec[j+4], q5 = ec[j+5], q6 = ec[j+6], q7 = ec[j+7];
        float4 x0 = x4[(size_t)q0.x * STR4 + xo];
        float4 x1 = x4[(size_t)q1.x * STR4 + xo];
        float4 x2 = x4[(size_t)q2.x * STR4 + xo];
        float4 x3 = x4[(size_t)q3.x * STR4 + xo];
        float4 x5 = x4[(size_t)q4.x * STR4 + xo];
        float4 x6 = x4[(size_t)q5.x * STR4 + xo];
        float4 x7 = x4[(size_t)q6.x * STR4 + xo];
        float4 x8 = x4[(size_t)q7.x * STR4 + xo];
        float v0 = nvd[q0.y], v1 = nvd[q1.y], v2 = nvd[q2.y], v3 = nvd[q3.y];
        float v4 = nvd[q4.y], v5 = nvd[q5.y], v6 = nvd[q6.y], v7 = nvd[q7.y];
        a[0] = fma4(v0, x0, a[0]);
        a[1] = fma4(v1, x1, a[1]);
        a[2] = fma4(v2, x2, a[2]);
        a[3] = fma4(v3, x3, a[3]);
        a[0] = fma4(v4, x5, a[0]);
        a[1] = fma4(v5, x6, a[1]);
        a[2] = fma4(v6, x7, a[2]);
        a[3] = fma4(v7, x8, a[3]);
    }
    for (; j + 4 <= p1; j += 4) {
        int2 q0 = ec[j], q1 = ec[j+1], q2 = ec[j+2], q3 = ec[j+3];
        float v0 = nvd[q0.y], v1 = nvd[q1.y], v2 = nvd[q2.y], v3 = nvd[q3.y];
        a[0] = fma4(v0, x4[(size_t)q0.x * STR4 + xo], a[0]);
        a[1] = fma4(v1, x4[(size_t)q1.x * STR4 + xo], a[1]);
        a[2] = fma4(v2, x4[(size_t)q2.x * STR4 + xo], a[2]);
        a[3] = fma4(v3, x4[(size_t)q3.x * STR4 + xo], a[3]);
    }
    for (; j < p1; j++) {
        int2 q = ec[j];
        a[0] = fma4(nvd[q.y], x4[(size_t)q.x * STR4 + xo], a[0]);
    }
}

// ---------- gen SpMM fused with node scores ----------
__global__ __launch_bounds__(256) void spmm64_scores(
    const int* __restrict__ rp_d, const int2* __restrict__ e1, const int2* __restrict__ e2,
    const float* __restrict__ Pg, const float* __restrict__ Wm1,
    const float* __restrict__ Wm2, float* __restrict__ sb)
{
    int y = blockIdx.y;
    const int* rp = rp_d + y * (NN + 1);
    const int2* arr = y ? e2 : e1;
    int row = blockIdx.x * 16 + threadIdx.x / 16;
    int o = threadIdx.x % 16;
    if (row >= NN) return;
    float4 a[4] = {};
    gath_dir_f32<32>(rp, arr, row, (const float4*)Pg, y * 16 + o, a);
    float4 r;
    r.x = fmaxf((a[0].x + a[1].x) + (a[2].x + a[3].x), 0.f);
    r.y = fmaxf((a[0].y + a[1].y) + (a[2].y + a[3].y), 0.f);
    r.z = fmaxf((a[0].z + a[1].z) + (a[2].z + a[3].z), 0.f);
    r.w = fmaxf((a[0].w + a[1].w) + (a[2].w + a[3].w), 0.f);
    const float* Wmh = (y ? Wm2 : Wm1) + GH;  // second half (sa & bm cancel)
    float part = r.x * Wmh[o * 4] + r.y * Wmh[o * 4 + 1]
               + r.z * Wmh[o * 4 + 2] + r.w * Wmh[o * 4 + 3];
    part += __shfl_xor(part, 1); part += __shfl_xor(part, 2);
    part += __shfl_xor(part, 4); part += __shfl_xor(part, 8);
    if (o == 0) sb[y * NN + row] = part;
}

// ---------- softmax epilogue ----------
__device__ __forceinline__ void softmax16_epi(
    float4 r, int node, float* __restrict__ logits, float* __restrict__ wout)
{
    int o = threadIdx.x & 3;
    float mx = fmaxf(fmaxf(r.x, r.y), fmaxf(r.z, r.w));
    mx = fmaxf(mx, __shfl_xor(mx, 1));
    mx = fmaxf(mx, __shfl_xor(mx, 2));
    float e0 = expf(r.x - mx), e1 = expf(r.y - mx), e2 = expf(r.z - mx), e3 = expf(r.w - mx);
    float s = (e0 + e1) + (e2 + e3);
    s += __shfl_xor(s, 1);
    s += __shfl_xor(s, 2);
    float inv = 1.f / s;
    float p0 = e0 * inv, p1 = e1 * inv, p2 = e2 * inv, p3 = e3 * inv;
    float4 lg;
    lg.x = logf(p0 + EPSc); lg.y = logf(p1 + EPSc);
    lg.z = logf(p2 + EPSc); lg.w = logf(p3 + EPSc);
    ((float4*)logits)[(size_t)node * 4 + o] = lg;
    if (wout) {
        float f = p0, se = -1.f;
        if (p1 > f) { se = f; f = p1; } else se = p1;
        if (p2 > f) { se = f; f = p2; } else if (p2 > se) se = p2;
        if (p3 > f) { se = f; f = p3; } else if (p3 > se) se = p3;
#pragma unroll
        for (int d = 1; d <= 2; d <<= 1) {
            float of = __shfl_xor(f, d), os = __shfl_xor(se, d);
            if (of > f) { se = fmaxf(f, os); f = of; }
            else se = fmaxf(se, of);
        }
        if (o == 0)
            wout[node] = expf(0.5f * logf(f + EPSc) + 0.5f * logf(f - se + EPSc));
    }
}

// ---------- pair body (branches 0/1 layer-2 + softmax + w12) ----------
__device__ __forceinline__ void pair_body(
    int y, int bx, const int* __restrict__ rp_d, const int* __restrict__ rp_c,
    const int2* __restrict__ ed1, const int2* __restrict__ ec1, const float* __restrict__ nvd1,
    const int2* __restrict__ ed2, const int2* __restrict__ ec2, const float* __restrict__ nvd2,
    const float* __restrict__ R01, float* __restrict__ logits_base, float* __restrict__ w12)
{
    const int* rpd = rp_d + y * (NN + 1);
    const int* rpc = rp_c + y * (NN + 1);
    const int2* ed = y ? ed2 : ed1;
    const int2* ec = y ? ec2 : ec1;
    const float* nvd = y ? nvd2 : nvd1;
    int row = bx * 64 + threadIdx.x / 4;
    int o = threadIdx.x % 4;
    if (row >= NN) return;
    const float4* x4 = (const float4*)(R01 + (size_t)y * NN * 16);
    float4 a[4] = {};
    gath_dir_f32<4>(rpd, ed, row, x4, o, a);
    gath_csc_f32<4>(rpc, ec, nvd, row, x4, o, a);
    float4 r;
    r.x = (a[0].x + a[1].x) + (a[2].x + a[3].x);
    r.y = (a[0].y + a[1].y) + (a[2].y + a[3].y);
    r.z = (a[0].z + a[1].z) + (a[2].z + a[3].z);
    r.w = (a[0].w + a[1].w) + (a[2].w + a[3].w);
    softmax16_epi(r, row, logits_base + (size_t)y * NN * NCLS, w12 + (size_t)y * NN);
}

// ---------- fused body (branch 2 layer-2 + softmax) ----------
__device__ __forceinline__ void fused_body(
    int bx, const int* __restrict__ rp_d, const int* __restrict__ rp_c,
    const int2* __restrict__ ed1, const int2* __restrict__ ec1, const float* __restrict__ nvd1,
    const int2* __restrict__ ed2, const int2* __restrict__ ec2, const float* __restrict__ nvd2,
    const float* __restrict__ w12, const float* __restrict__ x, float* __restrict__ logits)
{
    int row = bx * 64 + threadIdx.x / 4;
    int o = threadIdx.x % 4;
    if (row >= NN) return;
    const float4* x4 = (const float4*)x;
    float4 a[4] = {};
    gath_dir_f32<4>(rp_d, ed1, row, x4, o, a);
    gath_csc_f32<4>(rp_c, ec1, nvd1, row, x4, o, a);
    float4 s1;
    s1.x = (a[0].x + a[1].x) + (a[2].x + a[3].x);
    s1.y = (a[0].y + a[1].y) + (a[2].y + a[3].y);
    s1.z = (a[0].z + a[1].z) + (a[2].z + a[3].z);
    s1.w = (a[0].w + a[1].w) + (a[2].w + a[3].w);
    float4 b[4] = {};
    gath_dir_f32<4>(rp_d + (NN + 1), ed2, row, x4, o, b);
    gath_csc_f32<4>(rp_c + (NN + 1), ec2, nvd2, row, x4, o, b);
    float4 s2;
    s2.x = (b[0].x + b[1].x) + (b[2].x + b[3].x);
    s2.y = (b[0].y + b[1].y) + (b[2].y + b[3].y);
    s2.z = (b[0].z + b[1].z) + (b[2].z + b[3].z);
    s2.w = (b[0].w + b[1].w) + (b[2].w + b[3].w);
    float wa = w12[row], wb = w12[NN + row];
    float inv = 1.f / (wa + wb);
    float w1 = wa * inv, w2 = wb * inv;
    float4 r;
    r.x = w1 * s1.x + w2 * s2.x;
    r.y = w1 * s1.y + w2 * s2.y;
    r.z = w1 * s1.z + w2 * s2.z;
    r.w = w1 * s1.w + w2 * s2.w;
    softmax16_epi(r, row, logits, nullptr);
}

// ---------- bf16 gather helpers (8-deep) ----------
__device__ __forceinline__ void gath_dir_b16(
    const int* __restrict__ rp, const int2* __restrict__ ed, int row,
    const unsigned short* __restrict__ X, int xstride, int o, float* acc)
{
    int p0 = rp[row], p1 = rp[row + 1];
    int j = p0;
    for (; j + 8 <= p1; j += 8) {
        int2 q[8]; short8 x[8];
#pragma unroll
        for (int e = 0; e < 8; e++) q[e] = ed[j + e];
#pragma unroll
        for (int e = 0; e < 8; e++)
            x[e] = *(const short8*)&X[(size_t)q[e].x * xstride + o * 8];
#pragma unroll
        for (int e = 0; e < 8; e++) {
            float v = __int_as_float(q[e].y);
#pragma unroll
            for (int k = 0; k < 8; k++)
                acc[k] = fmaf(v, bf2f((unsigned short)x[e][k]), acc[k]);
        }
    }
    for (; j + 4 <= p1; j += 4) {
        int2 q0 = ed[j], q1 = ed[j+1], q2 = ed[j+2], q3 = ed[j+3];
        short8 x0 = *(const short8*)&X[(size_t)q0.x * xstride + o * 8];
        short8 x1 = *(const short8*)&X[(size_t)q1.x * xstride + o * 8];
        short8 x2 = *(const short8*)&X[(size_t)q2.x * xstride + o * 8];
        short8 x3 = *(const short8*)&X[(size_t)q3.x * xstride + o * 8];
        float v0 = __int_as_float(q0.y), v1 = __int_as_float(q1.y);
        float v2 = __int_as_float(q2.y), v3 = __int_as_float(q3.y);
#pragma unroll
        for (int k = 0; k < 8; k++) {
            acc[k] = fmaf(v0, bf2f((unsigned short)x0[k]), acc[k]);
            acc[k] = fmaf(v1, bf2f((unsigned short)x1[k]), acc[k]);
            acc[k] = fmaf(v2, bf2f((unsigned short)x2[k]), acc[k]);
            acc[k] = fmaf(v3, bf2f((unsigned short)x3[k]), acc[k]);
        }
    }
    for (; j < p1; j++) {
        int2 q = ed[j];
        short8 xv = *(const short8*)&X[(size_t)q.x * xstride + o * 8];
        float v = __int_as_float(q.y);
#pragma unroll
        for (int k = 0; k < 8; k++)
            acc[k] = fmaf(v, bf2f((unsigned short)xv[k]), acc[k]);
    }
}
__device__ __forceinline__ void gath_csc_b16(
    const int* __restrict__ rp, const int2* __restrict__ ec, const float* __restrict__ nvd,
    int row, const unsigned short* __restrict__ X, int xstride, int o, float* acc)
{
    int p0 = rp[row], p1 = rp[row + 1];
    int j = p0;
    for (; j + 8 <= p1; j += 8) {
        int2 q[8]; short8 x[8];
#pragma unroll
        for (int e = 0; e < 8; e++) q[e] = ec[j + e];
#pragma unroll
        for (int e = 0; e < 8; e++)
            x[e] = *(const short8*)&X[(size_t)q[e].x * xstride + o * 8];
        float v[8];
#pragma unroll
        for (int e = 0; e < 8; e++) v[e] = nvd[q[e].y];
#pragma unroll
        for (int e = 0; e < 8; e++) {
#pragma unroll
            for (int k = 0; k < 8; k++)
                acc[k] = fmaf(v[e], bf2f((unsigned short)x[e][k]), acc[k]);
        }
    }
    for (; j + 4 <= p1; j += 4) {
        int2 q0 = ec[j], q1 = ec[j+1], q2 = ec[j+2], q3 = ec[j+3];
        short8 x0 = *(const short8*)&X[(size_t)q0.x * xstride + o * 8];
        short8 x1 = *(const short8*)&X[(size_t)q1.x * xstride + o * 8];
        short8 x2 = *(const short8*)&X[(size_t)q2.x * xstride + o * 8];
        short8 x3 = *(const short8*)&X[(size_t)q3.x * xstride + o * 8];
        float v0 = nvd[q0.y], v1 = nvd[q1.y], v2 = nvd[q2.y], v3 = nvd[q3.y];
#pragma unroll
        for (int k = 0; k < 8; k++) {
            acc[k] = fmaf(v0, bf2f((unsigned short)x0[k]), acc[k]);
            acc[k] = fmaf(v1, bf2f((unsigned short)x1[k]), acc[k]);
            acc[k] = fmaf(v2, bf2f((unsigned short)x2[k]), acc[k]);
            acc[k] = fmaf(v3, bf2f((unsigned short)x3[k]), acc[k]);
        }
    }
    for (; j < p1; j++) {
        int2 q = ec[j];
        short8 xv = *(const short8*)&X[(size_t)q.x * xstride + o * 8];
        float v = nvd[q.y];
#pragma unroll
        for (int k = 0; k < 8; k++)
            acc[k] = fmaf(v, bf2f((unsigned short)xv[k]), acc[k]);
    }
}

// ---------- rows (MI) body, y=1,2 ----------
__device__ __forceinline__ void rows_b16_body(
    int bx, int y, const int* __restrict__ rp_d, const int* __restrict__ rp_c,
    const int2* __restrict__ ed1, const int2* __restrict__ ec1, const float* __restrict__ nvd1,
    const int2* __restrict__ ed2, const int2* __restrict__ ec2, const float* __restrict__ nvd2,
    const int* __restrict__ rows,
    const unsigned short* __restrict__ Pmi, float* __restrict__ zQ)
{
    int ri = bx * 16 + threadIdx.x / 16;
    int o = threadIdx.x % 16;
    if (ri >= BT) return;
    int node = rows[ri];
    int xoff = (y == 1) ? 128 : 256;
    const unsigned short* X = Pmi + xoff;
    float acc[8] = {};
    if (y == 1) {
        gath_dir_b16(rp_d, ed1, node, X, 384, o, acc);
        gath_csc_b16(rp_c, ec1, nvd1, node, X, 384, o, acc);
    } else {
        gath_dir_b16(rp_d + (NN + 1), ed2, node, X, 384, o, acc);
        gath_csc_b16(rp_c + (NN + 1), ec2, nvd2, node, X, 384, o, acc);
    }
    float* out = zQ + ((size_t)y * BT + ri) * 128 + o * 8;
#pragma unroll
    for (int k = 0; k < 8; k++) out[k] = fmaxf(acc[k], 0.f);
}

// ---------- rows y=0: raw per-view gathers ----------
__device__ __forceinline__ void rows0_gather_body(
    int bx, const int* __restrict__ rp_d, const int* __restrict__ rp_c,
    const int2* __restrict__ ed1, const int2* __restrict__ ec1, const float* __restrict__ nvd1,
    const int2* __restrict__ ed2, const int2* __restrict__ ec2, const float* __restrict__ nvd2,
    const int* __restrict__ rows, const unsigned short* __restrict__ Pmi,
    float* __restrict__ G1, float* __restrict__ G2)
{
    int ri = bx * 16 + threadIdx.x / 16;
    int o = threadIdx.x % 16;
    if (ri >= BT) return;
    int node = rows[ri];
    float g1[8] = {}, g2[8] = {};
    gath_dir_b16(rp_d, ed1, node, Pmi, 384, o, g1);
    gath_csc_b16(rp_c, ec1, nvd1, node, Pmi, 384, o, g1);
    gath_dir_b16(rp_d + (NN + 1), ed2, node, Pmi, 384, o, g2);
    gath_csc_b16(rp_c + (NN + 1), ec2, nvd2, node, Pmi, 384, o, g2);
    float* o1 = G1 + (size_t)ri * 128 + o * 8;
    float* o2 = G2 + (size_t)ri * 128 + o * 8;
    *(float4*)&o1[0] = make_float4(g1[0], g1[1], g1[2], g1[3]);
    *(float4*)&o1[4] = make_float4(g1[4], g1[5], g1[6], g1[7]);
    *(float4*)&o2[0] = make_float4(g2[0], g2[1], g2[2], g2[3]);
    *(float4*)&o2[4] = make_float4(g2[4], g2[5], g2[6], g2[7]);
}

// ---------- branch2: raw per-view gathers over Ph2 ----------
__device__ __forceinline__ void b2gather_body(
    int bx, const int* __restrict__ rp_d, const int* __restrict__ rp_c,
    const int2* __restrict__ ed1, const int2* __restrict__ ec1, const float* __restrict__ nvd1,
    const int2* __restrict__ ed2, const int2* __restrict__ ec2, const float* __restrict__ nvd2,
    const unsigned short* __restrict__ Ph2,
    float* __restrict__ A1, float* __restrict__ A2)
{
    int r = threadIdx.x / 16;
    int o = threadIdx.x % 16;
    int row = bx * 16 + r;
    if (row >= NN) return;
    float a1[8] = {}, a2[8] = {};
    gath_dir_b16(rp_d, ed1, row, Ph2, 128, o, a1);
    gath_csc_b16(rp_c, ec1, nvd1, row, Ph2, 128, o, a1);
    gath_dir_b16(rp_d + (NN + 1), ed2, row, Ph2, 128, o, a2);
    gath_csc_b16(rp_c + (NN + 1), ec2, nvd2, row, Ph2, 128, o, a2);
    float* o1 = A1 + (size_t)row * 128 + o * 8;
    float* o2 = A2 + (size_t)row * 128 + o * 8;
    *(float4*)&o1[0] = make_float4(a1[0], a1[1], a1[2], a1[3]);
    *(float4*)&o1[4] = make_float4(a1[4], a1[5], a1[6], a1[7]);
    *(float4*)&o2[0] = make_float4(a2[0], a2[1], a2[2], a2[3]);
    *(float4*)&o2[4] = make_float4(a2[4], a2[5], a2[6], a2[7]);
}

// ---------- spmm128 fp32 + fused L2 ----------
__device__ __forceinline__ void spmm128f_body(
    float* sm, int bx, int y, const int* __restrict__ rp_d, const int* __restrict__ rp_c,
    const int2* __restrict__ ed, const int2* __restrict__ ec, const float* __restrict__ nvd,
    const float* __restrict__ P01, const float* __restrict__ W2, float* __restrict__ R01)
{
    float* W2s = sm;            // 2048
    float* Qs  = sm + 2048;     // 8*128
    for (int i = threadIdx.x; i < 2048; i += 256) W2s[i] = W2[i];
    int r = threadIdx.x / 32;
    int o = threadIdx.x % 32;
    int row = bx * 8 + r;
    float4 a[4] = {};
    if (row < NN) {
        gath_dir_f32<64>(rp_d + y * (NN + 1), ed, row, (const float4*)P01, y * 32 + o, a);
        gath_csc_f32<64>(rp_c + y * (NN + 1), ec, nvd, row, (const float4*)P01, y * 32 + o, a);
    }
    float4 q;
    q.x = fmaxf((a[0].x + a[1].x) + (a[2].x + a[3].x), 0.f);
    q.y = fmaxf((a[0].y + a[1].y) + (a[2].y + a[3].y), 0.f);
    q.z = fmaxf((a[0].z + a[1].z) + (a[2].z + a[3].z), 0.f);
    q.w = fmaxf((a[0].w + a[1].w) + (a[2].w + a[3].w), 0.f);
    *(float4*)&Qs[r * 128 + o * 4] = q;
    __syncthreads();
    int t = threadIdx.x;
    if (t < 128) {
        int rr = t >> 4, c = t & 15;
        int grow = bx * 8 + rr;
        if (grow < NN) {
            float acc = 0.f;
            const float* qrow = &Qs[rr * 128];
#pragma unroll 8
            for (int k = 0; k < 128; k++)
                acc = fmaf(qrow[k], W2s[k * 16 + c], acc);
            R01[((size_t)y * NN + grow) * 16 + c] = acc;
        }
    }
}

// ---------- mega2: spmm128f (y=0,1) || rows y=1,2 (round-3 verified) ----------
__global__ __launch_bounds__(256) void mega2(
    const int* __restrict__ rp_d, const int* __restrict__ rp_c,
    const int2* __restrict__ ed1, const int2* __restrict__ ec1, const float* __restrict__ nvd1,
    const int2* __restrict__ ed2, const int2* __restrict__ ec2, const float* __restrict__ nvd2,
    const float* __restrict__ P01, const float* __restrict__ W2v1, const float* __restrict__ W2v2,
    float* __restrict__ R01,
    const int* __restrict__ rows, const unsigned short* __restrict__ Pmi,
    float* __restrict__ zQ)
{
    __shared__ float sm[2048 + 8 * 128];
    int b = blockIdx.x;
    if (b < 2 * SPB8) {
        int y = b / SPB8;
        spmm128f_body(sm, b % SPB8, y, rp_d, rp_c, y ? ed2 : ed1, y ? ec2 : ec1,
                      y ? nvd2 : nvd1, P01, y ? W2v2 : W2v1, R01);
        return;
    }
    b -= 2 * SPB8;
    int y = 1 + b / RBc;
    rows_b16_body(b % RBc, y, rp_d, rp_c, ed1, ec1, nvd1, ed2, ec2, nvd2,
                  rows, Pmi, zQ);
}

// ---------- proj body (8 rows/block, W amortized) ----------
__device__ __forceinline__ void proj8_body(
    float* g, float* u, float* red, int bx, int plane,
    const float* __restrict__ zQ,
    const float* __restrict__ Wp1, const float* __restrict__ bp1,
    const float* __restrict__ Wp2, const float* __restrict__ bp2,
    unsigned short* __restrict__ z16)
{
    int t = threadIdx.x;
    size_t base = (size_t)plane * BT + (size_t)bx * 8;
    for (int idx = t; idx < 8 * MH; idx += 256)
        g[idx] = zQ[(base + (idx >> 7)) * MH + (idx & 127)];
    __syncthreads();
    int col = t & 127;
    int rh = t >> 7;
    float acc[4];
    float b1 = bp1[col];
#pragma unroll
    for (int rr = 0; rr < 4; rr++) acc[rr] = b1;
    for (int k = 0; k < MH; k++) {
        float wk = Wp1[k * MH + col];
#pragma unroll
        for (int rr = 0; rr < 4; rr++)
            acc[rr] = fmaf(g[(rh * 4 + rr) * MH + k], wk, acc[rr]);
    }
#pragma unroll
    for (int rr = 0; rr < 4; rr++)
        u[(rh * 4 + rr) * MH + col] = acc[rr] > 0.f ? acc[rr] : (expf(acc[rr]) - 1.f);
    __syncthreads();
    float z[4];
    float b2 = bp2[col];
#pragma unroll
    for (int rr = 0; rr < 4; rr++) z[rr] = b2;
    for (int k = 0; k < MH; k++) {
        float wk = Wp2[k * MH + col];
#pragma unroll
        for (int rr = 0; rr < 4; rr++)
            z[rr] = fmaf(u[(rh * 4 + rr) * MH + k], wk, z[rr]);
    }
    float sq[4];
#pragma unroll
    for (int rr = 0; rr < 4; rr++) sq[rr] = z[rr] * z[rr];
#pragma unroll
    for (int off = 32; off; off >>= 1) {
#pragma unroll
        for (int rr = 0; rr < 4; rr++) sq[rr] += __shfl_xor(sq[rr], off);
    }
    int w = t >> 6;
    if ((t & 63) == 0) {
#pragma unroll
        for (int rr = 0; rr < 4; rr++) red[w * 4 + rr] = sq[rr];
    }
    __syncthreads();
#pragma unroll
    for (int rr = 0; rr < 4; rr++) {
        float nrm = sqrtf(red[(rh * 2) * 4 + rr] + red[(rh * 2 + 1) * 4 + rr]);
        z16[(base + rh * 4 + rr) * MH + col] = f2bf(z[rr] / nrm);
    }
}

// ---------- pairX: pair || b2gather || rows0-gather || proj planes 1,2 ----------
__global__ __launch_bounds__(256) void pairX(
    const int* __restrict__ rp_d, const int* __restrict__ rp_c,
    const int2* __restrict__ ed1, const int2* __restrict__ ec1, const float* __restrict__ nvd1,
    const int2* __restrict__ ed2, const int2* __restrict__ ec2, const float* __restrict__ nvd2,
    const float* __restrict__ R01, float* __restrict__ logits_base, float* __restrict__ w12,
    const unsigned short* __restrict__ Ph2, float* __restrict__ A1, float* __restrict__ A2,
    const int* __restrict__ rows, const unsigned short* __restrict__ Pmi,
    float* __restrict__ G1, float* __restrict__ G2,
    const float* __restrict__ zQ,
    const float* __restrict__ Wp1, const float* __restrict__ bp1,
    const float* __restrict__ Wp2, const float* __restrict__ bp2,
    unsigned short* __restrict__ z16)
{
    __shared__ float psm[2064];
    int b = blockIdx.x;
    int u = b >> 2, r = b & 3;
    if (r == 0) {
        if (u < 2 * PRB)
            pair_body(u / PRB, u % PRB, rp_d, rp_c, ed1, ec1, nvd1, ed2, ec2, nvd2,
                      R01, logits_base, w12);
        return;
    }
    int idx = u * 3 + (r - 1);
    if (idx < SPB16) {
        b2gather_body(idx, rp_d, rp_c, ed1, ec1, nvd1, ed2, ec2, nvd2, Ph2, A1, A2);
        return;
    }
    idx -= SPB16;
    if (idx < RBc) {
        rows0_gather_body(idx, rp_d, rp_c, ed1, ec1, nvd1, ed2, ec2, nvd2,
                          rows, Pmi, G1, G2);
        return;
    }
    idx -= RBc;
    if (idx < 2 * PJB) {
        int plane = 1 + idx / PJB;
        proj8_body(psm, psm + 1024, psm + 2048, idx % PJB, plane,
                   zQ, Wp1, bp1, Wp2, bp2, z16);
    }
}

// ---------- combineB2: w12-weighted combine (+W2 GEMM for branch2) ----------
__global__ __launch_bounds__(256) void combineB2(
    const float* __restrict__ w12,
    const float* __restrict__ A1, const float* __restrict__ A2,
    const float* __restrict__ W2v, float* __restrict__ R2,
    const int* __restrict__ rows,
    const float* __restrict__ G1, const float* __restrict__ G2,
    float* __restrict__ zQ)
{
    __shared__ float sm[2048 + 16 * 128];
    int b = blockIdx.x;
    int r = threadIdx.x / 16;
    int o = threadIdx.x % 16;
    if (b < SPB16) {
        float* W2s = sm;
        float* Qs  = sm + 2048;
        for (int i = threadIdx.x; i < 2048; i += 256) W2s[i] = W2v[i];
        int row = b * 16 + r;
        float wa = w12[row], wb = w12[NN + row];
        float inv = 1.f / (wa + wb);
        float w1 = wa * inv, w2 = wb * inv;
        const float* p1 = A1 + (size_t)row * 128 + o * 8;
        const float* p2 = A2 + (size_t)row * 128 + o * 8;
#pragma unroll
        for (int k = 0; k < 8; k++)
            Qs[r * 128 + o * 8 + k] = fmaxf(w1 * p1[k] + w2 * p2[k], 0.f);
        __syncthreads();
        int t = threadIdx.x;
        int rr = t >> 4, c = t & 15;
        int grow = b * 16 + rr;
        float acc = 0.f;
        const float* qrow = &Qs[rr * 128];
#pragma unroll 8
        for (int k = 0; k < 128; k++)
            acc = fmaf(qrow[k], W2s[k * 16 + c], acc);
        R2[(size_t)grow * 16 + c] = acc;
        return;
    }
    b -= SPB16;
    int ri = b * 16 + r;
    if (ri >= BT) return;
    int node = rows[ri];
    float wa = w12[node], wb = w12[NN + node];
    float inv = 1.f / (wa + wb);
    float w1 = wa * inv, w2 = wb * inv;
    const float* p1 = G1 + (size_t)ri * 128 + o * 8;
    const float* p2 = G2 + (size_t)ri * 128 + o * 8;
    float* out = zQ + (size_t)ri * 128 + o * 8;
#pragma unroll
    for (int k = 0; k < 8; k++)
        out[k] = fmaxf(w1 * p1[k] + w2 * p2[k], 0.f);
}

// ---------- fusedX: branch-2 softmax || proj plane 0 ----------
__global__ __launch_bounds__(256) void fusedX(
    const int* __restrict__ rp_d, const int* __restrict__ rp_c,
    const int2* __restrict__ ed1, const int2* __restrict__ ec1, const float* __restrict__ nvd1,
    const int2* __restrict__ ed2, const int2* __restrict__ ec2, const float* __restrict__ nvd2,
    const float* __restrict__ w12, const float* __restrict__ R2, float* __restrict__ logits,
    const float* __restrict__ zQ,
    const float* __restrict__ Wp1, const float* __restrict__ bp1,
    const float* __restrict__ Wp2, const float* __restrict__ bp2,
    unsigned short* __restrict__ z16)
{
    __shared__ float psm[2064];
    int b = blockIdx.x;
    if (b < PRB) {
        fused_body(b, rp_d, rp_c, ed1, ec1, nvd1, ed2, ec2, nvd2, w12, R2, logits);
        return;
    }
    proj8_body(psm, psm + 1024, psm + 2048, b - PRB, 0, zQ, Wp1, bp1, Wp2, bp2, z16);
}

__global__ void contrast_reduce(const float* __restrict__ stats, float* __restrict__ out3)
{
    int p = blockIdx.x, t = threadIdx.x;
    const float* diag = stats + (size_t)p * 3 * BT;
    const float* rs = diag + BT;
    const float* cs = rs + BT;
    float s1 = 0.f, s2 = 0.f;
    for (int i = t; i < BT; i += 256) {
        float d = diag[i];
        s1 += logf(d / (rs[i] + EPSc) + EPSc);
        s2 += logf(d / (cs[i] + EPSc) + EPSc);
    }
#pragma unroll
    for (int off = 32; off; off >>= 1) { s1 += __shfl_down(s1, off); s2 += __shfl_down(s2, off); }
    __shared__ float sh[8];
    if ((t & 63) == 0) { sh[(t >> 6) * 2] = s1; sh[(t >> 6) * 2 + 1] = s2; }
    __syncthreads();
    if (t == 0) {
        float a = sh[0] + sh[2] + sh[4] + sh[6];
        float b = sh[1] + sh[3] + sh[5] + sh[7];
        out3[p] = 0.5f * (-a / BT - b / BT);
    }
}

// ---------- host ----------
extern "C" void kernel_launch(void* const* d_in, const int* in_sizes, int n_in,
                              void* d_out, int out_size, void* d_ws, size_t ws_size,
                              hipStream_t stream)
{
    const float* feat   = (const float*)d_in[0];
    const int*   ind1   = (const int*)d_in[1];
    const float* vals1  = (const float*)d_in[2];
    const int*   ind2   = (const int*)d_in[3];
    const float* vals2  = (const float*)d_in[4];
    const int*   idxb   = (const int*)d_in[5];
    const float* Wm1    = (const float*)d_in[7];
    const float* Wm2    = (const float*)d_in[10];
    const float* W2_v1  = (const float*)d_in[13];
    const float* W2_v2  = (const float*)d_in[15];
    const float* W2_v   = (const float*)d_in[17];
    const float* Wp1    = (const float*)d_in[21];
    const float* bp1    = (const float*)d_in[22];
    const float* Wp2    = (const float*)d_in[23];
    const float* bp2    = (const float*)d_in[24];
    float* dout = (float*)d_out;

    float* ws = (float*)d_ws;
    size_t off = 0;
    auto alloc = [&](size_t n) { n = (n + 3) & ~(size_t)3; float* p = ws + off; off += n; return p; };
    auto alloc_s = [&](size_t n) { return (unsigned short*)alloc((n + 1) / 2); };

    // --- shared pool ---
    float* pool = alloc(16000000);
    float* Pg   = pool;                      // [0, 3.84M)  dead after spmm64_scores
    float* P01  = pool + 3840000;            // [3.84M, 11.52M)  [NN][256] f32
    float* R01  = pool + 11520000;           // [11.52M, 12.48M)
    float* zQ   = pool + 12480000;           // [12.48M, 14.05M)
    float* A1   = pool;                      // overlays Pg (written in pairX)
    float* G1   = pool + 14052864;           // [BT][128]
    float* G2   = pool + 14577152;           // [BT][128]
    float* R2   = pool + 15101440;           // [NN][16]

    // --- persistent ---
    unsigned short* feat_hi = alloc_s((size_t)NN * FD);
    unsigned short* feat_lo = alloc_s((size_t)NN * FD);
    float* A2 = (float*)feat_hi;             // feat splits dead after mega1x
    unsigned short* Ph2d    = alloc_s((size_t)NN * CH);
    unsigned short* Pmi16d  = alloc_s((size_t)NN * 384);
    float* sb   = alloc(2 * NN);
    float* w12  = alloc(2 * NN);
    float* stats = alloc((size_t)3 * 3 * BT);
    unsigned short* z16 = alloc_s((size_t)3 * BT * MH);
    int2* ed1 = (int2*)alloc(2 * (size_t)EE);
    int2* ed2 = (int2*)alloc(2 * (size_t)EE);
    int2* ec1 = (int2*)alloc(2 * (size_t)EE);
    int2* ec2 = (int2*)alloc(2 * (size_t)EE);
    float* nvd1 = alloc(EE);
    float* nvd2 = alloc(EE);
    int* sd1 = (int*)alloc(EE);
    int* sd2 = (int*)alloc(EE);
    int* sc1 = (int*)alloc(EE);
    int* sc2 = (int*)alloc(EE);
    int* rp4  = (int*)alloc(4 * (NN + 1));
    int* cnt4 = (int*)alloc(4 * NN);
    int* bsum = (int*)alloc(128);
    int* rp_d = rp4;
    int* rp_c = rp4 + 2 * (NN + 1);
    // weights (bf16 splits for K=256 GEMMs)
    unsigned short* wgen12h = alloc_s(32768); unsigned short* wgen12l = alloc_s(32768);
    unsigned short* w1pairh = alloc_s(65536); unsigned short* w1pairl = alloc_s(65536);
    unsigned short* w1vh    = alloc_s(32768); unsigned short* w1vl    = alloc_s(32768);
    unsigned short* wgallh  = alloc_s(98304); unsigned short* wgalll  = alloc_s(98304);

    const int NB = (NN + 1 + 1023) / 1024;
    const int NCNT = (EE + 255) / 256;

    // ---- prep: split || wsplit || count ----
    hipMemsetAsync(cnt4, 0, 4 * NN * 4, stream);
    WSArgs a;
    a.s[0] = (const float*)d_in[6];  a.h[0] = wgen12h;          a.l[0] = wgen12l;
    a.s[1] = (const float*)d_in[9];  a.h[1] = wgen12h + 16384;  a.l[1] = wgen12l + 16384;
    a.s[2] = (const float*)d_in[12]; a.h[2] = w1pairh;          a.l[2] = w1pairl;
    a.s[3] = (const float*)d_in[14]; a.h[3] = w1pairh + 32768;  a.l[3] = w1pairl + 32768;
    a.s[4] = (const float*)d_in[16]; a.h[4] = w1vh;             a.l[4] = w1vl;
    a.s[5] = (const float*)d_in[18]; a.h[5] = wgallh;           a.l[5] = wgalll;
    a.s[6] = (const float*)d_in[19]; a.h[6] = wgallh + 32768;   a.l[6] = wgalll + 32768;
    a.s[7] = (const float*)d_in[20]; a.h[7] = wgallh + 65536;   a.l[7] = wgalll + 65536;
    prep_all<<<30000 + 896 + NCNT, 256, 0, stream>>>(feat, feat_hi, feat_lo, a,
                                                     ind1, ind2, cnt4, sd1, sd2, sc1, sc2);

    // ---- scans ----
    scan_block4<<<dim3(NB, 4), 1024, 0, stream>>>(cnt4, rp4, bsum);
    scan_bsum4<<<4, 64, 0, stream>>>(bsum, NB);
    scan_add4<<<dim3(NB, 4), 1024, 0, stream>>>(bsum, rp4);

    // ---- mega1x: all GEMMs || placement ----
    mega1x<<<7 * GBc + NCNT, 256, 0, stream>>>(ind1, vals1, ind2, vals2,
                                               sd1, sd2, sc1, sc2, rp4,
                                               ed1, ec1, ed2, ec2,
                                               feat_hi, feat_lo, wgen12h, wgen12l, Pg,
                                               w1pairh, w1pairl, P01,
                                               w1vh, Ph2d, wgallh, Pmi16d);

    // ---- gen_view ----
    spmm64_scores<<<dim3((NN + 15) / 16, 2), 256, 0, stream>>>(rp_d, ed1, ed2, Pg, Wm1, Wm2, sb);
    gen_nv<<<dim3((NN + 255) / 256, 2), 256, 0, stream>>>(rp_d, ed1, ed2, sb, nvd1, nvd2);
    hipMemsetAsync(stats, 0, (size_t)3 * 3 * BT * 4, stream);

    // ---- mega2: branch01 spmm+L2 || mi rows y=1,2 (runs alone — fetch-bound) ----
    mega2<<<2 * SPB8 + 2 * RBc, 256, 0, stream>>>(rp_d, rp_c, ed1, ec1, nvd1,
                                                  ed2, ec2, nvd2, P01, W2_v1, W2_v2,
                                                  R01, idxb, Pmi16d, zQ);

    // ---- pairX: pair softmax+w12 || b2gather || rows0 gather || proj planes 1,2 ----
    pairX<<<4 * PX4, 256, 0, stream>>>(rp_d, rp_c, ed1, ec1, nvd1, ed2, ec2, nvd2,
                                       R01, dout + (size_t)NN * NCLS, w12,
                                       Ph2d, A1, A2, idxb, Pmi16d, G1, G2,
                                       zQ, Wp1, bp1, Wp2, bp2, z16);

    // ---- combine: branch2 mix + W2 GEMM -> R2 ; rows y=0 mix -> zQ ----
    combineB2<<<SPB16 + RBc, 256, 0, stream>>>(w12, A1, A2, W2_v, R2, idxb, G1, G2, zQ);

    // ---- fusedX: branch 2 softmax || proj plane 0 ----
    fusedX<<<PRB + PJB, 256, 0, stream>>>(rp_d, rp_c, ed1, ec1, nvd1, ed2, ec2, nvd2,
                                          w12, R2, dout, zQ, Wp1, bp1, Wp2, bp2, z16);

    // ---- contrast ----
    contrast_direct<<<dim3(32, 32, 3), 256, 0, stream>>>(z16, stats);
    contrast_reduce<<<3, 256, 0, stream>>>(stats, dout + (size_t)3 * NN * NCLS);
}